// Round 8
// baseline (1186.209 us; speedup 1.0000x reference)
//
#include <hip/hip_runtime.h>
#include <cmath>

// ---------------- problem constants ----------------
constexpr int N = 20000, T = 13, E = 320000;
constexpr int NB_SCAN = (N + 255) / 256;   // 79
constexpr int NPART = 64;                  // BN-sum partial buffers (atomic contention spread)
typedef unsigned int uint32;

typedef __attribute__((ext_vector_type(8))) short short8;   // 8 bf16 = 4 VGPRs
typedef __attribute__((ext_vector_type(4))) float f32x4;    // MFMA C/D frag

// ---------------- bf16 helpers ----------------
__device__ __forceinline__ unsigned short f2bf(float f) {
  unsigned int u = __float_as_uint(f);
  unsigned int r = (u + 0x7FFFu + ((u >> 16) & 1u)) >> 16;
  return (unsigned short)r;
}
__device__ __forceinline__ float bflo(uint32 v) { return __uint_as_float(v << 16); }
__device__ __forceinline__ float bfhi(uint32 v) { return __uint_as_float(v & 0xFFFF0000u); }
__device__ __forceinline__ uint32 packbf(float lo, float hi) {
  return (uint32)f2bf(lo) | ((uint32)f2bf(hi) << 16);
}

// ---------------- workspace layout ----------------
// Activations are node-major: row = n*T + t (proven fastest for the edge-gather hops:
// one random gather pulls a 768B contiguous row -> full cache-line utilization).
constexpr size_t WALIGN = 512;
constexpr size_t align_up(size_t x) { return (x + WALIGN - 1) & ~(WALIGN - 1); }

constexpr size_t XA_OFF  = 0;
constexpr size_t X_SZ    = align_up((size_t)N * 13 * 32 * 4);
constexpr size_t XB_OFF  = XA_OFF + X_SZ;
constexpr size_t H_OFF   = XB_OFF + X_SZ;
constexpr size_t H_SZ    = align_up((size_t)N * 12 * 32 * 4);
constexpr size_t C1_OFF  = H_OFF + H_SZ;
constexpr size_t C2_OFF  = C1_OFF + H_SZ;
constexpr size_t C3_OFF  = C2_OFF + H_SZ;     // (buffer now unused; kept for layout stability)
constexpr size_t HL_OFF  = C3_OFF + H_SZ;
constexpr size_t HL_SZ   = align_up((size_t)N * 256 * 4);
constexpr size_t W2P_OFF = HL_OFF + HL_SZ;                       // out2_w bf16 pack (8192 u32)
constexpr size_t SB_OFF  = W2P_OFF + align_up(8192 * 4);
constexpr size_t SUMS_OFF = SB_OFF + align_up(256 * 4);          // 8 layers x NPART x 64 floats
constexpr size_t PAR_OFF  = SUMS_OFF + align_up(8 * NPART * 64 * 4);   // unused (kept)
constexpr size_t CNT_OFF  = PAR_OFF + align_up(9 * 64 * 4);
constexpr size_t ROW_OFF  = CNT_OFF + align_up((size_t)N * 4);
constexpr size_t FILL_OFF = ROW_OFF + align_up((size_t)(N + 1) * 4);
constexpr size_t COL_OFF  = FILL_OFF + align_up((size_t)N * 4);
constexpr size_t DEG_OFF  = COL_OFF + align_up((size_t)E * 4);
constexpr size_t BP_OFF   = DEG_OFF + align_up((size_t)N * 4);   // gc_w B-frag pack
constexpr size_t CP_OFF   = BP_OFF + align_up(8 * 2048 * 4);     // unused (kept)
constexpr size_t BW1_OFF  = CP_OFF + align_up(8 * 2176 * 4);     // skip_w B-frag pack (O=256)
constexpr size_t BW2_OFF  = BW1_OFF + align_up(32768 * 4);       // out1_w B-frag pack (O=512)
constexpr size_t BS_OFF   = BW2_OFF + align_up(65536 * 4);       // scan partials
// aliases used after all layers are done:
constexpr size_t S_OFF  = C2_OFF;   // N*128 uint32 (bf16 S)

// ---------------- mega-setup kernel: all independent init/prep work in one launch ----------
// block ranges (each block = 256 threads)
constexpr int SU_CNT1 = 20;              // CNT zero (5000 int4)
constexpr int SU_SUM1 = SU_CNT1 + 32;    // SUMS zero (8192 float4)
constexpr int SU_OUT1 = SU_SUM1 + 469;   // d_out zero (120000 float4)
constexpr int SU_GCW1 = SU_OUT1 + 64;    // gc_w pack (16384)
constexpr int SU_BW11 = SU_GCW1 + 128;   // skip_w -> BW1 pack (32768)
constexpr int SU_BW21 = SU_BW11 + 256;   // out1_w -> BW2 pack (65536)
constexpr int SU_W21  = SU_BW21 + 32;    // out2_w -> W2P pack (8192)
constexpr int SU_SB1  = SU_W21 + 1;      // skip_b sum (256)
constexpr int SU_EN1  = SU_SB1 + 16250;  // enter conv (4160000)

__global__ __launch_bounds__(256) void k_setup(
    const float* __restrict__ inputs, const float* __restrict__ enter_w, const float* __restrict__ enter_b,
    const float* __restrict__ gc_w, const float* __restrict__ skip_w, const float* __restrict__ skip_b,
    const float* __restrict__ out1_w, const float* __restrict__ out2_w,
    int* __restrict__ cnt, float* __restrict__ sums,
    float* __restrict__ dout, int out_sz,
    uint32* __restrict__ bp, uint32* __restrict__ bw1,
    uint32* __restrict__ bw2, uint32* __restrict__ w2p, float* __restrict__ sbias,
    uint32* __restrict__ x) {
  int b = blockIdx.x, tid = threadIdx.x;
  if (b < SU_CNT1) {
    int i = b * 256 + tid;
    if (i < 5000) ((int4*)cnt)[i] = make_int4(0, 0, 0, 0);
  } else if (b < SU_SUM1) {
    int i = (b - SU_CNT1) * 256 + tid;
    if (i < 8192) ((float4*)sums)[i] = make_float4(0.f, 0.f, 0.f, 0.f);
  } else if (b < SU_OUT1) {
    int i = (b - SU_SUM1) * 256 + tid;
    if (i < (out_sz >> 2)) ((float4*)dout)[i] = make_float4(0.f, 0.f, 0.f, 0.f);
  } else if (b < SU_GCW1) {
    int idx = (b - SU_OUT1) * 256 + tid;   // < 16384 exact
    int w4 = idx & 3, lane = (idx >> 2) & 63, hh = (idx >> 8) & 1, s = (idx >> 9) & 3, l = idx >> 11;
    int n = lane & 15, q = lane >> 4;
    int k0 = q * 8 + w4 * 2, o = hh * 16 + n;
    const float* g = gc_w + (((size_t)(l * 4 + s) * 32 + k0) * 32 + o);
    bp[idx] = packbf(g[0], g[32]);
  } else if (b < SU_BW11) {
    int idx = (b - SU_GCW1) * 256 + tid;   // < 32768 exact
    int w4 = idx & 3, lane = (idx >> 2) & 63, ks = (idx >> 8) & 7, ot = idx >> 11;
    int n = lane & 15, q = lane >> 4;
    int c = q * 8 + w4 * 2, o = ot * 16 + n;
    const float* wr = skip_w + ((size_t)ks * 256 + o) * 32 + c;
    bw1[idx] = packbf(wr[0], wr[1]);
  } else if (b < SU_BW21) {
    int idx = (b - SU_BW11) * 256 + tid;   // < 65536 exact
    int w4 = idx & 3, lane = (idx >> 2) & 63, ks = (idx >> 8) & 7, ot = idx >> 11;
    int n = lane & 15, q = lane >> 4;
    int k = ks * 32 + q * 8 + w4 * 2;
    const float* wr = out1_w + (size_t)(ot * 16 + n) * 256 + k;
    bw2[idx] = packbf(wr[0], wr[1]);
  } else if (b < SU_W21) {
    int idx = (b - SU_BW21) * 256 + tid;   // < 8192 exact
    int w4 = idx & 3, lane = (idx >> 2) & 63, ks = (idx >> 8) & 15, ot = idx >> 12;
    int n = lane & 15, q = lane >> 4;
    int k = ks * 32 + q * 8 + w4 * 2;
    int o = ot * 16 + n;
    float v0 = 0.0f, v1 = 0.0f;
    if (o < 24) { const float* wr = out2_w + (size_t)o * 512 + k; v0 = wr[0]; v1 = wr[1]; }
    w2p[idx] = packbf(v0, v1);
  } else if (b < SU_SB1) {
    float s = 0.0f;
    for (int l = 0; l < 8; l++) s += skip_b[l * 256 + tid];
    sbias[tid] = s;
  } else {
    int idx = (b - SU_SB1) * 256 + tid;    // < 4160000 exact
    int cw = idx & 15; int tmp = idx >> 4; int t = tmp % 13; int n = tmp / 13;
    int c0 = cw * 2;
    const float* ip = inputs + (size_t)n * (13 * 3) + t * 3;
    float v0 = enter_b[c0]     + enter_w[c0 * 3 + 0]       * ip[0] + enter_w[c0 * 3 + 1]       * ip[1] + enter_w[c0 * 3 + 2]       * ip[2];
    float v1 = enter_b[c0 + 1] + enter_w[(c0 + 1) * 3 + 0] * ip[0] + enter_w[(c0 + 1) * 3 + 1] * ip[1] + enter_w[(c0 + 1) * 3 + 2] * ip[2];
    x[idx] = packbf(v0, v1);
  }
}

// ---------------- CSR build ----------------
__global__ void k_count(const int* __restrict__ dst, int* __restrict__ cnt) {
  int i = blockIdx.x * 256 + threadIdx.x;
  if (i < E) atomicAdd(&cnt[dst[i]], 1);
}

// parallel scan, phase 1: per-block sums
__global__ __launch_bounds__(256) void k_scan1(const int* __restrict__ cnt, int* __restrict__ bsum) {
  __shared__ int sc[256];
  int t = threadIdx.x; int idx = blockIdx.x * 256 + t;
  int v = (idx < N) ? cnt[idx] : 0;
  sc[t] = v; __syncthreads();
  for (int off = 1; off < 256; off <<= 1) {
    int u = (t >= off) ? sc[t - off] : 0;
    __syncthreads();
    sc[t] += u;
    __syncthreads();
  }
  if (t == 255) bsum[blockIdx.x] = sc[255];
}

// phase 2 (merged): each block redundantly scans bsum in LDS, then per-element scan
__global__ __launch_bounds__(256) void k_scan3(const int* __restrict__ cnt, const int* __restrict__ bsum,
                                               int* __restrict__ rowptr, int* __restrict__ fill,
                                               float* __restrict__ deginv) {
  __shared__ int sc[256];
  __shared__ int bo[128];
  int t = threadIdx.x; int idx = blockIdx.x * 256 + t;
  if (t < 128) bo[t] = (t < NB_SCAN) ? bsum[t] : 0;
  int v = (idx < N) ? cnt[idx] : 0;
  sc[t] = v; __syncthreads();
  for (int off = 1; off < 128; off <<= 1) {
    int u1 = (t < 128 && t >= off) ? bo[t - off] : 0;
    int u2 = (t >= off) ? sc[t - off] : 0;
    __syncthreads();
    if (t < 128) bo[t] += u1;
    sc[t] += u2;
    __syncthreads();
  }
  // one more step for sc (needs 256 wide; bo only needs 128)
  {
    int u2 = (t >= 128) ? sc[t - 128] : 0;
    __syncthreads();
    sc[t] += u2;
    __syncthreads();
  }
  if (idx < N) {
    int myoff = bo[blockIdx.x] - bsum[blockIdx.x];   // exclusive offset of this block
    int run = myoff + sc[t] - v;
    rowptr[idx] = run; fill[idx] = run;
    deginv[idx] = 1.0f / (float)(v > 1 ? v : 1);
  }
  if (blockIdx.x == 0 && t == 0) rowptr[N] = bo[NB_SCAN - 1];
}

__global__ void k_scatter(const int* __restrict__ src, const int* __restrict__ dst,
                          int* __restrict__ fill, int* __restrict__ col) {
  int i = blockIdx.x * 256 + threadIdx.x;
  if (i < E) { int d = dst[i]; int p = atomicAdd(&fill[d], 1); col[p] = src[i]; }
}

// ---------------- gated dilated conv (MFMA) — BN-fold fused in-block -------------------------
// Replaces k_bnprep + cpack: each block reduces sums[layer-1] -> affine (sc,sh), folds sc into
// the raw conv weights per-lane (16 float4 loads, all L2-hit) and sh into the biases.
// hlast: bf16 [node][128], slice layer*16 + j. LAST=true: h is dead -> skip the h store.
template <int TIN, int TOUT, int D, bool LAST>
__global__ __launch_bounds__(256, 4) void k_conv(const uint32* __restrict__ x,
    const float* __restrict__ fw, const float* __restrict__ fb,
    const float* __restrict__ gw, const float* __restrict__ gb,
    const float* __restrict__ sums, const float* __restrict__ bng, const float* __restrict__ bnb,
    int layer,
    uint32* __restrict__ h, uint32* __restrict__ hlast) {
  constexpr int RS = 34;
  __shared__ float xst[128 * RS];
  __shared__ float pb[64];       // sc(32), sh(32)
  __shared__ float bias_s[64];   // [sel*32+o]
  __shared__ float red[256];
  int tid = threadIdx.x;
  int wave = tid >> 6, lane = tid & 63;
  int m = lane & 15, q = lane >> 4;
  int nrows = N * TOUT;
  int base = blockIdx.x * 128;

  // ---- BN affine of previous layer (identity at layer 0) ----
  if (layer == 0) {
    if (tid < 64) pb[tid] = (tid < 32) ? 1.0f : 0.0f;
  } else {
    const float* lp = sums + (size_t)(layer - 1) * NPART * 64;
    int o = tid & 63, grp = tid >> 6;
    float t1 = 0.f;
    for (int p = grp; p < NPART; p += 4) t1 += lp[p * 64 + o];
    red[grp * 64 + o] = t1;
    __syncthreads();
    if (tid < 64) red[tid] = red[tid] + red[64 + tid] + red[128 + tid] + red[192 + tid];
    __syncthreads();
    if (tid < 32) {
      float cnt = (float)N * (float)TIN;   // prev layer's element count (TIN == TOUT_prev)
      float mu = red[tid] / cnt;
      float var = red[32 + tid] / cnt - mu * mu;
      float sc = bng[(layer - 1) * 32 + tid] * rsqrtf(var + 1e-5f);
      pb[tid] = sc;
      pb[32 + tid] = bnb[(layer - 1) * 32 + tid] - mu * sc;
    }
  }
  __syncthreads();

  // ---- folded biases: bias_s[sel*32+o] = b[o] + sum_c (w0+w1)*sh[c] ----
  if (tid < 64) {
    int sel = tid >> 5, o = tid & 31;
    const float* w = sel ? gw : fw;
    const float* b = sel ? gb : fb;
    const float* wr = w + ((size_t)layer * 32 + o) * 64;   // [c][2]
    float s = b[layer * 32 + o];
    for (int c = 0; c < 32; c++) s += (wr[c * 2] + wr[c * 2 + 1]) * pb[32 + c];
    bias_s[tid] = s;
  }

  // ---- per-lane weight frags bf[sel][ktap][hh], scaled by sc[c] ----
  short8 bf[2][2][2];
#pragma unroll
  for (int sel = 0; sel < 2; sel++) {
    const float* w = sel ? gw : fw;
#pragma unroll
    for (int hh = 0; hh < 2; hh++) {
      int o = hh * 16 + m;
      const float* wr = w + ((size_t)layer * 32 + o) * 64;
      union { uint32 u[4]; short8 s8; } f0, f1;
#pragma unroll
      for (int w4 = 0; w4 < 4; w4++) {
        int c0 = q * 8 + w4 * 2;
        float4 v = *(const float4*)(wr + c0 * 2);   // {w[c0][0], w[c0][1], w[c0+1][0], w[c0+1][1]}
        float sc0 = pb[c0], sc1 = pb[c0 + 1];
        f0.u[w4] = packbf(v.x * sc0, v.z * sc1);    // ktap 0
        f1.u[w4] = packbf(v.y * sc0, v.w * sc1);    // ktap 1
      }
      bf[sel][0][hh] = f0.s8;
      bf[sel][1][hh] = f1.s8;
    }
  }
  __syncthreads();   // bias_s ready
  float fb0 = bias_s[m], fb1 = bias_s[16 + m], gb0 = bias_s[32 + m], gb1 = bias_s[48 + m];

#pragma unroll
  for (int tile = 0; tile < 2; tile++) {
    int row = base + wave * 32 + tile * 16 + m;
    bool valid = row < nrows;
    int rr = valid ? row : 0;
    int n = rr / TOUT, tt = rr - n * TOUT;
    const uint32* xr = x + ((size_t)n * TIN + tt) * 16 + q * 4;
    short8 a0 = {0,0,0,0,0,0,0,0}, aD = {0,0,0,0,0,0,0,0};
    if (valid) { a0 = *(const short8*)xr; aD = *(const short8*)(xr + D * 16); }
    f32x4 aF0 = {0.f,0.f,0.f,0.f}, aF1 = {0.f,0.f,0.f,0.f};
    f32x4 aG0 = {0.f,0.f,0.f,0.f}, aG1 = {0.f,0.f,0.f,0.f};
    aF0 = __builtin_amdgcn_mfma_f32_16x16x32_bf16(a0, bf[0][0][0], aF0, 0, 0, 0);
    aF0 = __builtin_amdgcn_mfma_f32_16x16x32_bf16(aD, bf[0][1][0], aF0, 0, 0, 0);
    aF1 = __builtin_amdgcn_mfma_f32_16x16x32_bf16(a0, bf[0][0][1], aF1, 0, 0, 0);
    aF1 = __builtin_amdgcn_mfma_f32_16x16x32_bf16(aD, bf[0][1][1], aF1, 0, 0, 0);
    aG0 = __builtin_amdgcn_mfma_f32_16x16x32_bf16(a0, bf[1][0][0], aG0, 0, 0, 0);
    aG0 = __builtin_amdgcn_mfma_f32_16x16x32_bf16(aD, bf[1][1][0], aG0, 0, 0, 0);
    aG1 = __builtin_amdgcn_mfma_f32_16x16x32_bf16(a0, bf[1][0][1], aG1, 0, 0, 0);
    aG1 = __builtin_amdgcn_mfma_f32_16x16x32_bf16(aD, bf[1][1][1], aG1, 0, 0, 0);
#pragma unroll
    for (int r = 0; r < 4; r++) {
      int lrow = wave * 32 + tile * 16 + q * 4 + r;
      float F0 = aF0[r] + fb0, G0 = aG0[r] + gb0;
      float F1 = aF1[r] + fb1, G1 = aG1[r] + gb1;
      float af0 = fabsf(F0), ef0 = __expf(-2.0f * af0);
      float th0 = copysignf((1.0f - ef0) / (1.0f + ef0), F0);
      float hv0 = th0 * (1.0f / (1.0f + __expf(-G0)));
      float af1 = fabsf(F1), ef1 = __expf(-2.0f * af1);
      float th1 = copysignf((1.0f - ef1) / (1.0f + ef1), F1);
      float hv1 = th1 * (1.0f / (1.0f + __expf(-G1)));
      xst[lrow * RS + m]      = hv0;
      xst[lrow * RS + 16 + m] = hv1;
    }
  }
  __syncthreads();
  {
    uint2* outp = (uint2*)h;
#pragma unroll
    for (int it = 0; it < 4; it++) {
      int l = it * 256 + tid;
      int g = base * 8 + l;
      if (g < nrows * 8) {
        int rl = l >> 3, j4 = l & 7;
        float2 a = *(const float2*)&xst[rl * RS + j4 * 4];
        float2 b = *(const float2*)&xst[rl * RS + j4 * 4 + 2];
        uint2 pv = make_uint2(packbf(a.x, a.y), packbf(b.x, b.y));
        if constexpr (!LAST) outp[g] = pv;
        int grow = base + rl;
        int node = grow / TOUT, tt = grow - node * TOUT;
        if (tt == TOUT - 1) {
          *(uint2*)(hlast + (size_t)node * 128 + layer * 16 + j4 * 2) = pv;
        }
      }
    }
  }
}

// ---------------- one diffusion hop: uint4 gathers, half-wave edge pairing for small rows ------
template <int CH>
__global__ __launch_bounds__(256) void k_hop(const uint32* __restrict__ in, uint32* __restrict__ out,
    const int* __restrict__ rowptr, const int* __restrict__ col, const float* __restrict__ deginv) {
  const uint4* src = (const uint4*)in;
  uint4* dst = (uint4*)out;
  int wid = (blockIdx.x * 256 + threadIdx.x) >> 6;
  int lane = threadIdx.x & 63;
  if (wid >= N) return;
  int s = rowptr[wid], e = rowptr[wid + 1];
  float aL0 = 0.f, aL1 = 0.f, aL2 = 0.f, aL3 = 0.f;
  float aH0 = 0.f, aH1 = 0.f, aH2 = 0.f, aH3 = 0.f;

  if constexpr (CH <= 32) {
    int half = lane >> 5, c = lane & 31;
    bool act = c < CH;
    int idx = s;
    for (; idx + 7 < e; idx += 8) {
      int e0 = col[idx + half], e1 = col[idx + half + 2];
      int e2 = col[idx + half + 4], e3 = col[idx + half + 6];
      if (act) {
        uint4 v0 = src[(size_t)e0 * CH + c];
        uint4 v1 = src[(size_t)e1 * CH + c];
        uint4 v2 = src[(size_t)e2 * CH + c];
        uint4 v3 = src[(size_t)e3 * CH + c];
        aL0 += (bflo(v0.x) + bflo(v1.x)) + (bflo(v2.x) + bflo(v3.x));
        aH0 += (bfhi(v0.x) + bfhi(v1.x)) + (bfhi(v2.x) + bfhi(v3.x));
        aL1 += (bflo(v0.y) + bflo(v1.y)) + (bflo(v2.y) + bflo(v3.y));
        aH1 += (bfhi(v0.y) + bfhi(v1.y)) + (bfhi(v2.y) + bfhi(v3.y));
        aL2 += (bflo(v0.z) + bflo(v1.z)) + (bflo(v2.z) + bflo(v3.z));
        aH2 += (bfhi(v0.z) + bfhi(v1.z)) + (bfhi(v2.z) + bfhi(v3.z));
        aL3 += (bflo(v0.w) + bflo(v1.w)) + (bflo(v2.w) + bflo(v3.w));
        aH3 += (bfhi(v0.w) + bfhi(v1.w)) + (bfhi(v2.w) + bfhi(v3.w));
      }
    }
    for (; idx + 1 < e; idx += 2) {
      int e0 = col[idx + half];
      if (act) {
        uint4 v = src[(size_t)e0 * CH + c];
        aL0 += bflo(v.x); aH0 += bfhi(v.x);
        aL1 += bflo(v.y); aH1 += bfhi(v.y);
        aL2 += bflo(v.z); aH2 += bfhi(v.z);
        aL3 += bflo(v.w); aH3 += bfhi(v.w);
      }
    }
    if (idx < e && half == 0 && act) {
      uint4 v = src[(size_t)col[idx] * CH + c];
      aL0 += bflo(v.x); aH0 += bfhi(v.x);
      aL1 += bflo(v.y); aH1 += bfhi(v.y);
      aL2 += bflo(v.z); aH2 += bfhi(v.z);
      aL3 += bflo(v.w); aH3 += bfhi(v.w);
    }
    aL0 += __shfl_xor(aL0, 32); aH0 += __shfl_xor(aH0, 32);
    aL1 += __shfl_xor(aL1, 32); aH1 += __shfl_xor(aH1, 32);
    aL2 += __shfl_xor(aL2, 32); aH2 += __shfl_xor(aH2, 32);
    aL3 += __shfl_xor(aL3, 32); aH3 += __shfl_xor(aH3, 32);
    float inv = deginv[wid];
    if (half == 0 && act) {
      uint4 o;
      o.x = packbf(aL0 * inv, aH0 * inv);
      o.y = packbf(aL1 * inv, aH1 * inv);
      o.z = packbf(aL2 * inv, aH2 * inv);
      o.w = packbf(aL3 * inv, aH3 * inv);
      dst[(size_t)wid * CH + c] = o;
    }
  } else {
    int c = lane;
    bool act = c < CH;
    int idx = s;
    for (; idx + 3 < e; idx += 4) {
      int e0 = col[idx], e1 = col[idx + 1], e2 = col[idx + 2], e3 = col[idx + 3];
      if (act) {
        uint4 v0 = src[(size_t)e0 * CH + c];
        uint4 v1 = src[(size_t)e1 * CH + c];
        uint4 v2 = src[(size_t)e2 * CH + c];
        uint4 v3 = src[(size_t)e3 * CH + c];
        aL0 += (bflo(v0.x) + bflo(v1.x)) + (bflo(v2.x) + bflo(v3.x));
        aH0 += (bfhi(v0.x) + bfhi(v1.x)) + (bfhi(v2.x) + bfhi(v3.x));
        aL1 += (bflo(v0.y) + bflo(v1.y)) + (bflo(v2.y) + bflo(v3.y));
        aH1 += (bfhi(v0.y) + bfhi(v1.y)) + (bfhi(v2.y) + bfhi(v3.y));
        aL2 += (bflo(v0.z) + bflo(v1.z)) + (bflo(v2.z) + bflo(v3.z));
        aH2 += (bfhi(v0.z) + bfhi(v1.z)) + (bfhi(v2.z) + bfhi(v3.z));
        aL3 += (bflo(v0.w) + bflo(v1.w)) + (bflo(v2.w) + bflo(v3.w));
        aH3 += (bfhi(v0.w) + bfhi(v1.w)) + (bfhi(v2.w) + bfhi(v3.w));
      }
    }
    for (; idx < e; ++idx) {
      int e0 = col[idx];
      if (act) {
        uint4 v = src[(size_t)e0 * CH + c];
        aL0 += bflo(v.x); aH0 += bfhi(v.x);
        aL1 += bflo(v.y); aH1 += bfhi(v.y);
        aL2 += bflo(v.z); aH2 += bfhi(v.z);
        aL3 += bflo(v.w); aH3 += bfhi(v.w);
      }
    }
    float inv = deginv[wid];
    if (act) {
      uint4 o;
      o.x = packbf(aL0 * inv, aH0 * inv);
      o.y = packbf(aL1 * inv, aH1 * inv);
      o.z = packbf(aL2 * inv, aH2 * inv);
      o.w = packbf(aL3 * inv, aH3 * inv);
      dst[(size_t)wid * CH + c] = o;
    }
  }
}

// ---------------- combine (MFMA) — hop3 fused (C3 gathered from C2 into LDS) + in-block BN ----
template <int TIN, int TOUT>
__global__ __launch_bounds__(256, 4) void k_combine(const uint32* __restrict__ h,
    const uint32* __restrict__ c1, const uint32* __restrict__ c2,
    const uint32* __restrict__ bpack, const float* __restrict__ gcb,
    const uint32* __restrict__ xcur, int layer,
    const float* __restrict__ bng, const float* __restrict__ bnb,
    const int* __restrict__ rowptr, const int* __restrict__ col, const float* __restrict__ deginv,
    uint32* __restrict__ xnext, float* __restrict__ sums) {
  constexpr int RS = 34;
  constexpr int RS3 = 20;           // c3 tile stride (keeps 16B alignment, spreads banks)
  __shared__ float xst[128 * RS];
  __shared__ uint32 c3s[128 * RS3];
  __shared__ float pbuf[96];        // gcb(32), sc(32), sh(32)
  __shared__ float red[256];
  __shared__ float r1s[32], r2s[32];
  int tid = threadIdx.x;
  int nrows = N * TOUT;
  int base = blockIdx.x * 128;
  int wave = tid >> 6, lane = tid & 63;
  int m = lane & 15, q = lane >> 4;
  if (tid < 32) {
    pbuf[tid] = gcb[layer * 32 + tid];
    r1s[tid] = 0.0f; r2s[tid] = 0.0f;
  }

  // ---- fused hop3: gather this block's C3 tile from C2 (item = row*16 + chunk) ----
#pragma unroll
  for (int it = 0; it < 8; it++) {
    int item = it * 256 + tid;
    int r = item >> 4, c = item & 15;
    int row = base + r;
    uint32 outv = 0;
    if (row < nrows) {
      int node = row / TOUT, t = row - node * TOUT;
      int s0 = rowptr[node], e0 = rowptr[node + 1];
      size_t off = (size_t)t * 16 + c;
      float alo = 0.f, ahi = 0.f;
      int idx = s0;
      for (; idx + 3 < e0; idx += 4) {
        uint32 v0 = c2[(size_t)col[idx]     * (TOUT * 16) + off];
        uint32 v1 = c2[(size_t)col[idx + 1] * (TOUT * 16) + off];
        uint32 v2 = c2[(size_t)col[idx + 2] * (TOUT * 16) + off];
        uint32 v3 = c2[(size_t)col[idx + 3] * (TOUT * 16) + off];
        alo += (bflo(v0) + bflo(v1)) + (bflo(v2) + bflo(v3));
        ahi += (bfhi(v0) + bfhi(v1)) + (bfhi(v2) + bfhi(v3));
      }
      for (; idx < e0; ++idx) {
        uint32 v = c2[(size_t)col[idx] * (TOUT * 16) + off];
        alo += bflo(v); ahi += bfhi(v);
      }
      float inv = deginv[node];
      outv = packbf(alo * inv, ahi * inv);
    }
    c3s[r * RS3 + c] = outv;
  }

  // ---- BN affine of previous layer (identity at layer 0) ----
  if (layer == 0) {
    if (tid < 64) pbuf[32 + tid] = (tid < 32) ? 1.0f : 0.0f;
  } else {
    const float* lp = sums + (size_t)(layer - 1) * NPART * 64;
    int o = tid & 63, grp = tid >> 6;
    float t1 = 0.f;
    for (int p = grp; p < NPART; p += 4) t1 += lp[p * 64 + o];
    red[grp * 64 + o] = t1;
    __syncthreads();
    if (tid < 64) red[tid] = red[tid] + red[64 + tid] + red[128 + tid] + red[192 + tid];
    __syncthreads();
    if (tid < 32) {
      float cnt = (float)N * (float)TIN;
      float mu = red[tid] / cnt;
      float var = red[32 + tid] / cnt - mu * mu;
      float sc = bng[(layer - 1) * 32 + tid] * rsqrtf(var + 1e-5f);
      pbuf[32 + tid] = sc;
      pbuf[64 + tid] = bnb[(layer - 1) * 32 + tid] - mu * sc;
    }
  }
  __syncthreads();   // c3s + pbuf ready

  const uint32* bp = bpack + (size_t)layer * 2048;
  short8 bf[4][2];
#pragma unroll
  for (int s = 0; s < 4; s++)
#pragma unroll
    for (int hh = 0; hh < 2; hh++)
      bf[s][hh] = *(const short8*)(bp + (size_t)((s * 2 + hh) * 64 + lane) * 4);

  f32x4 acc[2][2] = {{{0.f,0.f,0.f,0.f},{0.f,0.f,0.f,0.f}},{{0.f,0.f,0.f,0.f},{0.f,0.f,0.f,0.f}}};
  const uint32* srcs[3] = { h, c1, c2 };
#pragma unroll
  for (int s = 0; s < 4; s++) {
#pragma unroll
    for (int t = 0; t < 2; t++) {
      int row = base + wave * 32 + t * 16 + m;
      short8 af = {0,0,0,0,0,0,0,0};
      if (s < 3) {
        if (row < nrows) af = *(const short8*)(srcs[s] + (size_t)row * 16 + q * 4);
      } else {
        af = *(const short8*)&c3s[(wave * 32 + t * 16 + m) * RS3 + q * 4];
      }
      acc[t][0] = __builtin_amdgcn_mfma_f32_16x16x32_bf16(af, bf[s][0], acc[t][0], 0, 0, 0);
      acc[t][1] = __builtin_amdgcn_mfma_f32_16x16x32_bf16(af, bf[s][1], acc[t][1], 0, 0, 0);
    }
  }

  __syncthreads();
#pragma unroll
  for (int t = 0; t < 2; t++)
#pragma unroll
    for (int hh = 0; hh < 2; hh++)
#pragma unroll
      for (int r = 0; r < 4; r++)
        xst[(wave * 32 + t * 16 + q * 4 + r) * RS + hh * 16 + m] = acc[t][hh][r];
  __syncthreads();

  constexpr int toff = TIN - TOUT;
  int rg = tid >> 3, oq = tid & 7;
  float gb0 = pbuf[oq * 4 + 0], gb1 = pbuf[oq * 4 + 1], gb2 = pbuf[oq * 4 + 2], gb3 = pbuf[oq * 4 + 3];
  float sc0 = pbuf[32 + oq * 4 + 0], sc1 = pbuf[32 + oq * 4 + 1], sc2 = pbuf[32 + oq * 4 + 2], sc3 = pbuf[32 + oq * 4 + 3];
  float sh0 = pbuf[64 + oq * 4 + 0], sh1 = pbuf[64 + oq * 4 + 1], sh2 = pbuf[64 + oq * 4 + 2], sh3 = pbuf[64 + oq * 4 + 3];
  float s1[4] = {0.f, 0.f, 0.f, 0.f}, s2[4] = {0.f, 0.f, 0.f, 0.f};
#pragma unroll
  for (int i = 0; i < 4; i++) {
    int r = rg + 32 * i;
    int row = base + r;
    bool act = row < nrows;
    float2 aa = *(const float2*)&xst[r * RS + oq * 4];
    float2 ab = *(const float2*)&xst[r * RS + oq * 4 + 2];
    float xr0 = 0.f, xr1 = 0.f, xr2 = 0.f, xr3 = 0.f;
    if (act) {
      int node = row / TOUT, t_ = row - node * TOUT;
      const uint32* rp = xcur + ((size_t)node * TIN + toff + t_) * 16 + oq * 2;
      uint32 va = rp[0], vb = rp[1];
      xr0 = bflo(va); xr1 = bfhi(va); xr2 = bflo(vb); xr3 = bfhi(vb);
    }
    float v0 = aa.x + gb0 + sc0 * xr0 + sh0;
    float v1 = aa.y + gb1 + sc1 * xr1 + sh1;
    float v2 = ab.x + gb2 + sc2 * xr2 + sh2;
    float v3 = ab.y + gb3 + sc3 * xr3 + sh3;
    *(float2*)&xst[r * RS + oq * 4]     = make_float2(v0, v1);
    *(float2*)&xst[r * RS + oq * 4 + 2] = make_float2(v2, v3);
    if (act) {
      s1[0] += v0; s1[1] += v1; s1[2] += v2; s1[3] += v3;
      s2[0] += v0 * v0; s2[1] += v1 * v1; s2[2] += v2 * v2; s2[3] += v3 * v3;
    }
  }
#pragma unroll
  for (int j = 0; j < 4; j++) {
    atomicAdd(&r1s[oq * 4 + j], s1[j]);
    atomicAdd(&r2s[oq * 4 + j], s2[j]);
  }
  __syncthreads();

  {
    uint2* outp = (uint2*)xnext;
#pragma unroll
    for (int it = 0; it < 4; it++) {
      int l = it * 256 + tid;
      int g = base * 8 + l;
      if (g < nrows * 8) {
        int rl = l >> 3, j4 = l & 7;
        float2 a = *(const float2*)&xst[rl * RS + j4 * 4];
        float2 b = *(const float2*)&xst[rl * RS + j4 * 4 + 2];
        outp[g] = make_uint2(packbf(a.x, a.y), packbf(b.x, b.y));
      }
    }
  }
  // BN partial atomics spread over NPART buffers: sums[(layer*NPART+part)*64 + j]
  {
    int part = blockIdx.x & (NPART - 1);
    float* sp = sums + ((size_t)layer * NPART + part) * 64;
    if (tid < 32) atomicAdd(&sp[tid], r1s[tid]);
    else if (tid < 64) atomicAdd(&sp[tid], r2s[tid - 32]);
  }
}

// ---------------- head GEMM 1: S = relu(HLbf @ WS2^T + SB), bf16 in, bf16 out ----------------
__global__ __launch_bounds__(256) void k_gemm1(const uint32* __restrict__ A,
    const uint32* __restrict__ bp, const float* __restrict__ bias, uint32* __restrict__ Sb) {
  constexpr int RS = 68;
  __shared__ float xst[128 * RS];
  int tid = threadIdx.x;
  int wave = tid >> 6, lane = tid & 63;
  int m = lane & 15, q = lane >> 4;
  int base = blockIdx.x * 128;
  int ot0 = blockIdx.y * 8;

  f32x4 acc[2][8];
#pragma unroll
  for (int t = 0; t < 2; t++)
#pragma unroll
    for (int nt = 0; nt < 8; nt++) acc[t][nt] = (f32x4){0.f, 0.f, 0.f, 0.f};

  int row0 = base + wave * 32 + m;
  int row1 = row0 + 16;
#pragma unroll 1
  for (int ks = 0; ks < 8; ks++) {
    short8 a0 = {0,0,0,0,0,0,0,0}, a1 = {0,0,0,0,0,0,0,0};
    if (row0 < N) a0 = *(const short8*)(A + (size_t)row0 * 128 + ks * 16 + q * 4);
    if (row1 < N) a1 = *(const short8*)(A + (size_t)row1 * 128 + ks * 16 + q * 4);
#pragma unroll
    for (int nt = 0; nt < 8; nt++) {
      short8 b = *(const short8*)(bp + (size_t)(((ot0 + nt) * 8 + ks) * 64 + lane) * 4);
      acc[0][nt] = __builtin_amdgcn_mfma_f32_16x16x32_bf16(a0, b, acc[0][nt], 0, 0, 0);
      acc[1][nt] = __builtin_amdgcn_mfma_f32_16x16x32_bf16(a1, b, acc[1][nt], 0, 0, 0);
    }
  }

#pragma unroll
  for (int half = 0; half < 2; half++) {
    if (half) __syncthreads();
#pragma unroll
    for (int t = 0; t < 2; t++)
#pragma unroll
      for (int nn = 0; nn < 4; nn++) {
        float bv = bias[blockIdx.y * 128 + (half * 4 + nn) * 16 + m];
#pragma unroll
        for (int r = 0; r < 4; r++) {
          float v = acc[t][half * 4 + nn][r] + bv;
          xst[(wave * 32 + t * 16 + q * 4 + r) * RS + nn * 16 + m] = fmaxf(v, 0.0f);
        }
      }
    __syncthreads();
#pragma unroll
    for (int it = 0; it < 8; it++) {
      int l = it * 256 + tid;
      int rl = l >> 4, c4 = l & 15;
      int grow = base + rl;
      if (grow < N) {
        float2 a = *(const float2*)&xst[rl * RS + c4 * 4];
        float2 b = *(const float2*)&xst[rl * RS + c4 * 4 + 2];
        *(uint2*)(Sb + (size_t)grow * 128 + blockIdx.y * 64 + half * 32 + c4 * 2) =
            make_uint2(packbf(a.x, a.y), packbf(b.x, b.y));
      }
    }
  }
}

// ---------------- head GEMM 2 fused: out += relu(Sbf @ out1_w^T + b1) @ out2_w^T (+ b2) --------
__global__ __launch_bounds__(256) void k_gemm2f(const uint32* __restrict__ A,
    const uint32* __restrict__ bp, const float* __restrict__ bias,
    const uint32* __restrict__ w2p, const float* __restrict__ b2, float* __restrict__ out) {
  constexpr int RS = 68;
  __shared__ float xst[128 * RS];
  int tid = threadIdx.x;
  int wave = tid >> 6, lane = tid & 63;
  int m = lane & 15, q = lane >> 4;
  int base = blockIdx.x * 128;
  int ot0 = blockIdx.y * 8;

  f32x4 acc[2][8];
#pragma unroll
  for (int t = 0; t < 2; t++)
#pragma unroll
    for (int nt = 0; nt < 8; nt++) acc[t][nt] = (f32x4){0.f, 0.f, 0.f, 0.f};

  int row0 = base + wave * 32 + m;
  int row1 = row0 + 16;
#pragma unroll 1
  for (int ks = 0; ks < 8; ks++) {
    short8 a0 = {0,0,0,0,0,0,0,0}, a1 = {0,0,0,0,0,0,0,0};
    if (row0 < N) a0 = *(const short8*)(A + (size_t)row0 * 128 + ks * 16 + q * 4);
    if (row1 < N) a1 = *(const short8*)(A + (size_t)row1 * 128 + ks * 16 + q * 4);
#pragma unroll
    for (int nt = 0; nt < 8; nt++) {
      short8 b = *(const short8*)(bp + (size_t)(((ot0 + nt) * 8 + ks) * 64 + lane) * 4);
      acc[0][nt] = __builtin_amdgcn_mfma_f32_16x16x32_bf16(a0, b, acc[0][nt], 0, 0, 0);
      acc[1][nt] = __builtin_amdgcn_mfma_f32_16x16x32_bf16(a1, b, acc[1][nt], 0, 0, 0);
    }
  }

  f32x4 acc2[2][2];
#pragma unroll
  for (int t = 0; t < 2; t++)
#pragma unroll
    for (int o2 = 0; o2 < 2; o2++) acc2[t][o2] = (f32x4){0.f, 0.f, 0.f, 0.f};

#pragma unroll
  for (int half = 0; half < 2; half++) {
    if (half) __syncthreads();
#pragma unroll
    for (int t = 0; t < 2; t++)
#pragma unroll
      for (int nn = 0; nn < 4; nn++) {
        float bv = bias[blockIdx.y * 128 + (half * 4 + nn) * 16 + m];
#pragma unroll
        for (int r = 0; r < 4; r++) {
          float v = acc[t][half * 4 + nn][r] + bv;
          xst[(wave * 32 + t * 16 + q * 4 + r) * RS + nn * 16 + m] = fmaxf(v, 0.0f);
        }
      }
    __syncthreads();
#pragma unroll
    for (int kl = 0; kl < 2; kl++) {
      short8 a2[2];
#pragma unroll
      for (int t = 0; t < 2; t++) {
        const float* xp = &xst[(size_t)(wave * 32 + t * 16 + m) * RS + kl * 32 + q * 8];
        float4 f0 = *(const float4*)xp;
        float4 f1 = *(const float4*)(xp + 4);
        uint32 u[4];
        u[0] = packbf(f0.x, f0.y); u[1] = packbf(f0.z, f0.w);
        u[2] = packbf(f1.x, f1.y); u[3] = packbf(f1.z, f1.w);
        a2[t] = *(const short8*)u;
      }
      int ksg = blockIdx.y * 4 + half * 2 + kl;
#pragma unroll
      for (int o2 = 0; o2 < 2; o2++) {
        short8 b = *(const short8*)(w2p + (size_t)(((o2 * 16 + ksg) * 64 + lane) * 4));
        acc2[0][o2] = __builtin_amdgcn_mfma_f32_16x16x32_bf16(a2[0], b, acc2[0][o2], 0, 0, 0);
        acc2[1][o2] = __builtin_amdgcn_mfma_f32_16x16x32_bf16(a2[1], b, acc2[1][o2], 0, 0, 0);
      }
    }
  }

#pragma unroll
  for (int t = 0; t < 2; t++)
#pragma unroll
    for (int o2 = 0; o2 < 2; o2++) {
      int oc = o2 * 16 + m;
      if (oc < 24) {
#pragma unroll
        for (int r = 0; r < 4; r++) {
          int row = base + wave * 32 + t * 16 + q * 4 + r;
          if (row < N) {
            float v = acc2[t][o2][r];
            if (blockIdx.y == 0) v += b2[oc];
            atomicAdd(&out[(size_t)row * 24 + oc], v);
          }
        }
      }
    }
}

// ---------------- host side ----------------
struct Ptrs {
  const float *fw, *fb, *gw, *gb, *gcb, *bng, *bnb;
  const uint32 *bpack;
  void *H, *C1, *C2;
  uint32 *HL;
  float *sums;
  const int *row, *col;
  const float *deg;
};

template <int TIN, int TOUT, int D, bool LAST>
static void run_layer(int layer, const Ptrs& P, uint32*& xc, uint32*& xn, hipStream_t stream) {
  int cblocks = (N * TOUT + 127) / 128;
  k_conv<TIN, TOUT, D, LAST><<<cblocks, 256, 0, stream>>>(xc, P.fw, P.fb, P.gw, P.gb,
                                                          P.sums, P.bng, P.bnb, layer,
                                                          (uint32*)P.H, P.HL);
  if (!LAST) {
    constexpr int CH = TOUT * 4;   // uint4 chunks per row
    int hb = (N * 64 + 255) / 256;
    k_hop<CH><<<hb, 256, 0, stream>>>((const uint32*)P.H, (uint32*)P.C1, P.row, P.col, P.deg);
    k_hop<CH><<<hb, 256, 0, stream>>>((const uint32*)P.C1, (uint32*)P.C2, P.row, P.col, P.deg);
    k_combine<TIN, TOUT><<<cblocks, 256, 0, stream>>>((const uint32*)P.H, (const uint32*)P.C1,
                                                      (const uint32*)P.C2,
                                                      P.bpack, P.gcb, xc, layer,
                                                      P.bng, P.bnb, P.row, P.col, P.deg,
                                                      xn, P.sums);
    uint32* tmp = xc; xc = xn; xn = tmp;
  }
}

extern "C" void kernel_launch(void* const* d_in, const int* in_sizes, int n_in,
                              void* d_out, int out_size, void* d_ws, size_t ws_size,
                              hipStream_t stream) {
  const float* inputs  = (const float*)d_in[0];
  const int*   esrc    = (const int*)d_in[1];
  const int*   edst    = (const int*)d_in[2];
  const float* enter_w = (const float*)d_in[3];
  const float* enter_b = (const float*)d_in[4];
  const float* filt_w  = (const float*)d_in[5];
  const float* filt_b  = (const float*)d_in[6];
  const float* gate_w  = (const float*)d_in[7];
  const float* gate_b  = (const float*)d_in[8];
  const float* gc_w    = (const float*)d_in[9];
  const float* gc_b    = (const float*)d_in[10];
  const float* skip_w  = (const float*)d_in[11];
  const float* skip_b  = (const float*)d_in[12];
  const float* bn_g    = (const float*)d_in[13];
  const float* bn_b    = (const float*)d_in[14];
  const float* out1_w  = (const float*)d_in[15];
  const float* out1_b  = (const float*)d_in[16];
  const float* out2_w  = (const float*)d_in[17];
  const float* out2_b  = (const float*)d_in[18];

  char* ws = (char*)d_ws;
  uint32* XA = (uint32*)(ws + XA_OFF);
  uint32* XB = (uint32*)(ws + XB_OFF);
  void* H    = (void*)(ws + H_OFF);
  void* C1   = (void*)(ws + C1_OFF);
  void* C2   = (void*)(ws + C2_OFF);
  uint32* HLB = (uint32*)(ws + HL_OFF);     // bf16 [N][128]
  uint32* W2P = (uint32*)(ws + W2P_OFF);
  float* SB  = (float*)(ws + SB_OFF);
  float* SUMS = (float*)(ws + SUMS_OFF);
  int* CNT  = (int*)(ws + CNT_OFF);
  int* ROW  = (int*)(ws + ROW_OFF);
  int* FILL = (int*)(ws + FILL_OFF);
  int* COL  = (int*)(ws + COL_OFF);
  float* DEG = (float*)(ws + DEG_OFF);
  uint32* BP = (uint32*)(ws + BP_OFF);
  uint32* BW1 = (uint32*)(ws + BW1_OFF);
  uint32* BW2 = (uint32*)(ws + BW2_OFF);
  int* BS = (int*)(ws + BS_OFF);
  uint32* Sb  = (uint32*)(ws + S_OFF);      // bf16 S [N][128]

  // one mega-setup launch: zeros (CNT/SUMS/d_out), all weight packs, enter conv
  k_setup<<<SU_EN1, 256, 0, stream>>>(inputs, enter_w, enter_b,
                                      gc_w, skip_w, skip_b, out1_w, out2_w,
                                      CNT, SUMS, (float*)d_out, out_size,
                                      BP, BW1, BW2, W2P, SB, XA);

  k_count<<<(E + 255) / 256, 256, 0, stream>>>(edst, CNT);
  k_scan1<<<NB_SCAN, 256, 0, stream>>>(CNT, BS);
  k_scan3<<<NB_SCAN, 256, 0, stream>>>(CNT, BS, ROW, FILL, DEG);
  k_scatter<<<(E + 255) / 256, 256, 0, stream>>>(esrc, edst, FILL, COL);

  Ptrs P;
  P.fw = filt_w; P.fb = filt_b; P.gw = gate_w; P.gb = gate_b;
  P.gcb = gc_b; P.bng = bn_g; P.bnb = bn_b; P.bpack = BP;
  P.H = H; P.C1 = C1; P.C2 = C2; P.HL = HLB; P.sums = SUMS;
  P.row = ROW; P.col = COL; P.deg = DEG;

  uint32* xc = XA; uint32* xn = XB;
  run_layer<13, 12, 1, false>(0, P, xc, xn, stream);
  run_layer<12, 10, 2, false>(1, P, xc, xn, stream);
  run_layer<10, 9, 1, false>(2, P, xc, xn, stream);
  run_layer<9, 7, 2, false>(3, P, xc, xn, stream);
  run_layer<7, 6, 1, false>(4, P, xc, xn, stream);
  run_layer<6, 4, 2, false>(5, P, xc, xn, stream);
  run_layer<4, 3, 1, false>(6, P, xc, xn, stream);
  run_layer<3, 1, 2, true>(7, P, xc, xn, stream);

  // head: S = relu(HL @ WS2^T + SB) [bf16]; out = relu(S @ out1_w^T + b1) @ out2_w^T + b2 (fused)
  dim3 g1((N + 127) / 128, 2);
  k_gemm1<<<g1, 256, 0, stream>>>(HLB, BW1, SB, Sb);
  dim3 g2((N + 127) / 128, 4);
  k_gemm2f<<<g2, 256, 0, stream>>>(Sb, BW2, out1_b, W2P, out2_b, (float*)d_out);
}

// Round 9
// 1105.044 us; speedup vs baseline: 1.0734x; 1.0734x over previous
//
#include <hip/hip_runtime.h>
#include <cmath>

// ---------------- problem constants ----------------
constexpr int N = 20000, T = 13, E = 320000;
constexpr int NB_SCAN = (N + 255) / 256;   // 79
constexpr int NPART = 64;                  // BN-sum partial buffers (atomic contention spread)
typedef unsigned int uint32;

typedef __attribute__((ext_vector_type(8))) short short8;   // 8 bf16 = 4 VGPRs
typedef __attribute__((ext_vector_type(4))) float f32x4;    // MFMA C/D frag

// ---------------- bf16 helpers ----------------
__device__ __forceinline__ unsigned short f2bf(float f) {
  unsigned int u = __float_as_uint(f);
  unsigned int r = (u + 0x7FFFu + ((u >> 16) & 1u)) >> 16;
  return (unsigned short)r;
}
__device__ __forceinline__ float bflo(uint32 v) { return __uint_as_float(v << 16); }
__device__ __forceinline__ float bfhi(uint32 v) { return __uint_as_float(v & 0xFFFF0000u); }
__device__ __forceinline__ uint32 packbf(float lo, float hi) {
  return (uint32)f2bf(lo) | ((uint32)f2bf(hi) << 16);
}

// ---------------- workspace layout ----------------
// Activations are node-major: row = n*T + t (proven fastest for the edge-gather hops:
// one random gather pulls a 768B contiguous row -> full cache-line utilization).
constexpr size_t WALIGN = 512;
constexpr size_t align_up(size_t x) { return (x + WALIGN - 1) & ~(WALIGN - 1); }

constexpr size_t XA_OFF  = 0;
constexpr size_t X_SZ    = align_up((size_t)N * 13 * 32 * 4);
constexpr size_t XB_OFF  = XA_OFF + X_SZ;
constexpr size_t H_OFF   = XB_OFF + X_SZ;
constexpr size_t H_SZ    = align_up((size_t)N * 12 * 32 * 4);
constexpr size_t C1_OFF  = H_OFF + H_SZ;
constexpr size_t C2_OFF  = C1_OFF + H_SZ;
constexpr size_t C3_OFF  = C2_OFF + H_SZ;
constexpr size_t HL_OFF  = C3_OFF + H_SZ;
constexpr size_t HL_SZ   = align_up((size_t)N * 256 * 4);
constexpr size_t W2P_OFF = HL_OFF + HL_SZ;                       // out2_w bf16 pack (8192 u32)
constexpr size_t SB_OFF  = W2P_OFF + align_up(8192 * 4);
constexpr size_t SUMS_OFF = SB_OFF + align_up(256 * 4);          // 8 layers x NPART x 64 floats
constexpr size_t CNT_OFF  = SUMS_OFF + align_up(8 * NPART * 64 * 4);
constexpr size_t ROW_OFF  = CNT_OFF + align_up((size_t)N * 4);
constexpr size_t FILL_OFF = ROW_OFF + align_up((size_t)(N + 1) * 4);
constexpr size_t COL_OFF  = FILL_OFF + align_up((size_t)N * 4);
constexpr size_t DEG_OFF  = COL_OFF + align_up((size_t)E * 4);
constexpr size_t BP_OFF   = DEG_OFF + align_up((size_t)N * 4);   // gc_w B-frag pack
constexpr size_t BW1_OFF  = BP_OFF + align_up(8 * 2048 * 4);     // skip_w B-frag pack (O=256)
constexpr size_t BW2_OFF  = BW1_OFF + align_up(32768 * 4);       // out1_w B-frag pack (O=512)
constexpr size_t BS_OFF   = BW2_OFF + align_up(65536 * 4);       // scan partials
// aliases used after all layers are done:
constexpr size_t S_OFF  = C2_OFF;   // N*128 uint32 (bf16 S)

// ---------------- mega-setup kernel: all independent init/prep work in one launch ----------
// block ranges (each block = 256 threads)
constexpr int SU_CNT1 = 20;              // CNT zero (5000 int4)
constexpr int SU_SUM1 = SU_CNT1 + 32;    // SUMS zero (8192 float4)
constexpr int SU_OUT1 = SU_SUM1 + 469;   // d_out zero (120000 float4)
constexpr int SU_GCW1 = SU_OUT1 + 64;    // gc_w pack (16384)
constexpr int SU_BW11 = SU_GCW1 + 128;   // skip_w -> BW1 pack (32768)
constexpr int SU_BW21 = SU_BW11 + 256;   // out1_w -> BW2 pack (65536)
constexpr int SU_W21  = SU_BW21 + 32;    // out2_w -> W2P pack (8192)
constexpr int SU_SB1  = SU_W21 + 1;      // skip_b sum (256)
constexpr int SU_EN1  = SU_SB1 + 16250;  // enter conv (4160000)

__global__ __launch_bounds__(256) void k_setup(
    const float* __restrict__ inputs, const float* __restrict__ enter_w, const float* __restrict__ enter_b,
    const float* __restrict__ gc_w, const float* __restrict__ skip_w, const float* __restrict__ skip_b,
    const float* __restrict__ out1_w, const float* __restrict__ out2_w,
    int* __restrict__ cnt, float* __restrict__ sums,
    float* __restrict__ dout, int out_sz,
    uint32* __restrict__ bp, uint32* __restrict__ bw1,
    uint32* __restrict__ bw2, uint32* __restrict__ w2p, float* __restrict__ sbias,
    uint32* __restrict__ x) {
  int b = blockIdx.x, tid = threadIdx.x;
  if (b < SU_CNT1) {
    int i = b * 256 + tid;
    if (i < 5000) ((int4*)cnt)[i] = make_int4(0, 0, 0, 0);
  } else if (b < SU_SUM1) {
    int i = (b - SU_CNT1) * 256 + tid;
    if (i < 8192) ((float4*)sums)[i] = make_float4(0.f, 0.f, 0.f, 0.f);
  } else if (b < SU_OUT1) {
    int i = (b - SU_SUM1) * 256 + tid;
    if (i < (out_sz >> 2)) ((float4*)dout)[i] = make_float4(0.f, 0.f, 0.f, 0.f);
  } else if (b < SU_GCW1) {
    int idx = (b - SU_OUT1) * 256 + tid;   // < 16384 exact
    int w4 = idx & 3, lane = (idx >> 2) & 63, hh = (idx >> 8) & 1, s = (idx >> 9) & 3, l = idx >> 11;
    int n = lane & 15, q = lane >> 4;
    int k0 = q * 8 + w4 * 2, o = hh * 16 + n;
    const float* g = gc_w + (((size_t)(l * 4 + s) * 32 + k0) * 32 + o);
    bp[idx] = packbf(g[0], g[32]);
  } else if (b < SU_BW11) {
    int idx = (b - SU_GCW1) * 256 + tid;   // < 32768 exact
    int w4 = idx & 3, lane = (idx >> 2) & 63, ks = (idx >> 8) & 7, ot = idx >> 11;
    int n = lane & 15, q = lane >> 4;
    int c = q * 8 + w4 * 2, o = ot * 16 + n;
    const float* wr = skip_w + ((size_t)ks * 256 + o) * 32 + c;
    bw1[idx] = packbf(wr[0], wr[1]);
  } else if (b < SU_BW21) {
    int idx = (b - SU_BW11) * 256 + tid;   // < 65536 exact
    int w4 = idx & 3, lane = (idx >> 2) & 63, ks = (idx >> 8) & 7, ot = idx >> 11;
    int n = lane & 15, q = lane >> 4;
    int k = ks * 32 + q * 8 + w4 * 2;
    const float* wr = out1_w + (size_t)(ot * 16 + n) * 256 + k;
    bw2[idx] = packbf(wr[0], wr[1]);
  } else if (b < SU_W21) {
    int idx = (b - SU_BW21) * 256 + tid;   // < 8192 exact
    int w4 = idx & 3, lane = (idx >> 2) & 63, ks = (idx >> 8) & 15, ot = idx >> 12;
    int n = lane & 15, q = lane >> 4;
    int k = ks * 32 + q * 8 + w4 * 2;
    int o = ot * 16 + n;
    float v0 = 0.0f, v1 = 0.0f;
    if (o < 24) { const float* wr = out2_w + (size_t)o * 512 + k; v0 = wr[0]; v1 = wr[1]; }
    w2p[idx] = packbf(v0, v1);
  } else if (b < SU_SB1) {
    float s = 0.0f;
    for (int l = 0; l < 8; l++) s += skip_b[l * 256 + tid];
    sbias[tid] = s;
  } else {
    int idx = (b - SU_SB1) * 256 + tid;    // < 4160000 exact
    int cw = idx & 15; int tmp = idx >> 4; int t = tmp % 13; int n = tmp / 13;
    int c0 = cw * 2;
    const float* ip = inputs + (size_t)n * (13 * 3) + t * 3;
    float v0 = enter_b[c0]     + enter_w[c0 * 3 + 0]       * ip[0] + enter_w[c0 * 3 + 1]       * ip[1] + enter_w[c0 * 3 + 2]       * ip[2];
    float v1 = enter_b[c0 + 1] + enter_w[(c0 + 1) * 3 + 0] * ip[0] + enter_w[(c0 + 1) * 3 + 1] * ip[1] + enter_w[(c0 + 1) * 3 + 2] * ip[2];
    x[idx] = packbf(v0, v1);
  }
}

// ---------------- CSR build ----------------
__global__ void k_count(const int* __restrict__ dst, int* __restrict__ cnt) {
  int i = blockIdx.x * 256 + threadIdx.x;
  if (i < E) atomicAdd(&cnt[dst[i]], 1);
}

// parallel scan, phase 1: per-block sums
__global__ __launch_bounds__(256) void k_scan1(const int* __restrict__ cnt, int* __restrict__ bsum) {
  __shared__ int sc[256];
  int t = threadIdx.x; int idx = blockIdx.x * 256 + t;
  int v = (idx < N) ? cnt[idx] : 0;
  sc[t] = v; __syncthreads();
  for (int off = 1; off < 256; off <<= 1) {
    int u = (t >= off) ? sc[t - off] : 0;
    __syncthreads();
    sc[t] += u;
    __syncthreads();
  }
  if (t == 255) bsum[blockIdx.x] = sc[255];
}

// phase 2 (merged): each block redundantly scans bsum in LDS, then per-element scan
__global__ __launch_bounds__(256) void k_scan3(const int* __restrict__ cnt, const int* __restrict__ bsum,
                                               int* __restrict__ rowptr, int* __restrict__ fill,
                                               float* __restrict__ deginv) {
  __shared__ int sc[256];
  __shared__ int bo[128];
  int t = threadIdx.x; int idx = blockIdx.x * 256 + t;
  if (t < 128) bo[t] = (t < NB_SCAN) ? bsum[t] : 0;
  int v = (idx < N) ? cnt[idx] : 0;
  sc[t] = v; __syncthreads();
  for (int off = 1; off < 128; off <<= 1) {
    int u1 = (t < 128 && t >= off) ? bo[t - off] : 0;
    int u2 = (t >= off) ? sc[t - off] : 0;
    __syncthreads();
    if (t < 128) bo[t] += u1;
    sc[t] += u2;
    __syncthreads();
  }
  // one more step for sc (needs 256 wide; bo only needs 128)
  {
    int u2 = (t >= 128) ? sc[t - 128] : 0;
    __syncthreads();
    sc[t] += u2;
    __syncthreads();
  }
  if (idx < N) {
    int myoff = bo[blockIdx.x] - bsum[blockIdx.x];   // exclusive offset of this block
    int run = myoff + sc[t] - v;
    rowptr[idx] = run; fill[idx] = run;
    deginv[idx] = 1.0f / (float)(v > 1 ? v : 1);
  }
  if (blockIdx.x == 0 && t == 0) rowptr[N] = bo[NB_SCAN - 1];
}

__global__ void k_scatter(const int* __restrict__ src, const int* __restrict__ dst,
                          int* __restrict__ fill, int* __restrict__ col) {
  int i = blockIdx.x * 256 + threadIdx.x;
  if (i < E) { int d = dst[i]; int p = atomicAdd(&fill[d], 1); col[p] = src[i]; }
}

// ---------------- gated dilated conv (MFMA) — BN-fold fused in-block (k_bnprep eliminated) ----
// Each block reduces sums[layer-1] -> affine (sc,sh) (L2-hit, 16KB), folds sc into the raw
// conv weights per-lane and sh into the biases. hlast: bf16 [node][128], slice layer*16 + j.
template <int TIN, int TOUT, int D, bool LAST>
__global__ __launch_bounds__(256, 4) void k_conv(const uint32* __restrict__ x,
    const float* __restrict__ fw, const float* __restrict__ fb,
    const float* __restrict__ gw, const float* __restrict__ gb,
    const float* __restrict__ sums, const float* __restrict__ bng, const float* __restrict__ bnb,
    int layer,
    uint32* __restrict__ h, uint32* __restrict__ hlast) {
  constexpr int RS = 34;
  __shared__ float xst[128 * RS];
  __shared__ float pb[64];       // sc(32), sh(32)
  __shared__ float bias_s[64];   // [sel*32+o]
  __shared__ float red[256];
  int tid = threadIdx.x;
  int wave = tid >> 6, lane = tid & 63;
  int m = lane & 15, q = lane >> 4;
  int nrows = N * TOUT;
  int base = blockIdx.x * 128;

  // ---- BN affine of previous layer (identity at layer 0) ----
  if (layer == 0) {
    if (tid < 64) pb[tid] = (tid < 32) ? 1.0f : 0.0f;
  } else {
    const float* lp = sums + (size_t)(layer - 1) * NPART * 64;
    int o = tid & 63, grp = tid >> 6;
    float t1 = 0.f;
    for (int p = grp; p < NPART; p += 4) t1 += lp[p * 64 + o];
    red[grp * 64 + o] = t1;
    __syncthreads();
    if (tid < 64) red[tid] = red[tid] + red[64 + tid] + red[128 + tid] + red[192 + tid];
    __syncthreads();
    if (tid < 32) {
      float cnt = (float)N * (float)TIN;   // prev layer's element count (TIN == TOUT_prev)
      float mu = red[tid] / cnt;
      float var = red[32 + tid] / cnt - mu * mu;
      float sc = bng[(layer - 1) * 32 + tid] * rsqrtf(var + 1e-5f);
      pb[tid] = sc;
      pb[32 + tid] = bnb[(layer - 1) * 32 + tid] - mu * sc;
    }
  }
  __syncthreads();

  // ---- folded biases: bias_s[sel*32+o] = b[o] + sum_c (w0+w1)*sh[c] ----
  if (tid < 64) {
    int sel = tid >> 5, o = tid & 31;
    const float* w = sel ? gw : fw;
    const float* b = sel ? gb : fb;
    const float* wr = w + ((size_t)layer * 32 + o) * 64;   // [c][2]
    float s = b[layer * 32 + o];
    for (int c = 0; c < 32; c++) s += (wr[c * 2] + wr[c * 2 + 1]) * pb[32 + c];
    bias_s[tid] = s;
  }

  // ---- per-lane weight frags bf[sel][ktap][hh], scaled by sc[c] ----
  short8 bf[2][2][2];
#pragma unroll
  for (int sel = 0; sel < 2; sel++) {
    const float* w = sel ? gw : fw;
#pragma unroll
    for (int hh = 0; hh < 2; hh++) {
      int o = hh * 16 + m;
      const float* wr = w + ((size_t)layer * 32 + o) * 64;
      union { uint32 u[4]; short8 s8; } f0, f1;
#pragma unroll
      for (int w4 = 0; w4 < 4; w4++) {
        int c0 = q * 8 + w4 * 2;
        float4 v = *(const float4*)(wr + c0 * 2);   // {w[c0][0], w[c0][1], w[c0+1][0], w[c0+1][1]}
        float sc0 = pb[c0], sc1 = pb[c0 + 1];
        f0.u[w4] = packbf(v.x * sc0, v.z * sc1);    // ktap 0
        f1.u[w4] = packbf(v.y * sc0, v.w * sc1);    // ktap 1
      }
      bf[sel][0][hh] = f0.s8;
      bf[sel][1][hh] = f1.s8;
    }
  }
  __syncthreads();   // bias_s ready
  float fb0 = bias_s[m], fb1 = bias_s[16 + m], gb0 = bias_s[32 + m], gb1 = bias_s[48 + m];

#pragma unroll
  for (int tile = 0; tile < 2; tile++) {
    int row = base + wave * 32 + tile * 16 + m;
    bool valid = row < nrows;
    int rr = valid ? row : 0;
    int n = rr / TOUT, tt = rr - n * TOUT;
    const uint32* xr = x + ((size_t)n * TIN + tt) * 16 + q * 4;
    short8 a0 = {0,0,0,0,0,0,0,0}, aD = {0,0,0,0,0,0,0,0};
    if (valid) { a0 = *(const short8*)xr; aD = *(const short8*)(xr + D * 16); }
    f32x4 aF0 = {0.f,0.f,0.f,0.f}, aF1 = {0.f,0.f,0.f,0.f};
    f32x4 aG0 = {0.f,0.f,0.f,0.f}, aG1 = {0.f,0.f,0.f,0.f};
    aF0 = __builtin_amdgcn_mfma_f32_16x16x32_bf16(a0, bf[0][0][0], aF0, 0, 0, 0);
    aF0 = __builtin_amdgcn_mfma_f32_16x16x32_bf16(aD, bf[0][1][0], aF0, 0, 0, 0);
    aF1 = __builtin_amdgcn_mfma_f32_16x16x32_bf16(a0, bf[0][0][1], aF1, 0, 0, 0);
    aF1 = __builtin_amdgcn_mfma_f32_16x16x32_bf16(aD, bf[0][1][1], aF1, 0, 0, 0);
    aG0 = __builtin_amdgcn_mfma_f32_16x16x32_bf16(a0, bf[1][0][0], aG0, 0, 0, 0);
    aG0 = __builtin_amdgcn_mfma_f32_16x16x32_bf16(aD, bf[1][1][0], aG0, 0, 0, 0);
    aG1 = __builtin_amdgcn_mfma_f32_16x16x32_bf16(a0, bf[1][0][1], aG1, 0, 0, 0);
    aG1 = __builtin_amdgcn_mfma_f32_16x16x32_bf16(aD, bf[1][1][1], aG1, 0, 0, 0);
#pragma unroll
    for (int r = 0; r < 4; r++) {
      int lrow = wave * 32 + tile * 16 + q * 4 + r;
      float F0 = aF0[r] + fb0, G0 = aG0[r] + gb0;
      float F1 = aF1[r] + fb1, G1 = aG1[r] + gb1;
      float af0 = fabsf(F0), ef0 = __expf(-2.0f * af0);
      float th0 = copysignf((1.0f - ef0) / (1.0f + ef0), F0);
      float hv0 = th0 * (1.0f / (1.0f + __expf(-G0)));
      float af1 = fabsf(F1), ef1 = __expf(-2.0f * af1);
      float th1 = copysignf((1.0f - ef1) / (1.0f + ef1), F1);
      float hv1 = th1 * (1.0f / (1.0f + __expf(-G1)));
      xst[lrow * RS + m]      = hv0;
      xst[lrow * RS + 16 + m] = hv1;
    }
  }
  __syncthreads();
  {
    uint2* outp = (uint2*)h;
#pragma unroll
    for (int it = 0; it < 4; it++) {
      int l = it * 256 + tid;
      int g = base * 8 + l;
      if (g < nrows * 8) {
        int rl = l >> 3, j4 = l & 7;
        float2 a = *(const float2*)&xst[rl * RS + j4 * 4];
        float2 b = *(const float2*)&xst[rl * RS + j4 * 4 + 2];
        uint2 pv = make_uint2(packbf(a.x, a.y), packbf(b.x, b.y));
        if constexpr (!LAST) outp[g] = pv;
        int grow = base + rl;
        int node = grow / TOUT, tt = grow - node * TOUT;
        if (tt == TOUT - 1) {
          *(uint2*)(hlast + (size_t)node * 128 + layer * 16 + j4 * 2) = pv;
        }
      }
    }
  }
}

// ---------------- one diffusion hop: uint4 gathers, half-wave edge pairing for small rows ------
template <int CH>
__global__ __launch_bounds__(256) void k_hop(const uint32* __restrict__ in, uint32* __restrict__ out,
    const int* __restrict__ rowptr, const int* __restrict__ col, const float* __restrict__ deginv) {
  const uint4* src = (const uint4*)in;
  uint4* dst = (uint4*)out;
  int wid = (blockIdx.x * 256 + threadIdx.x) >> 6;
  int lane = threadIdx.x & 63;
  if (wid >= N) return;
  int s = rowptr[wid], e = rowptr[wid + 1];
  float aL0 = 0.f, aL1 = 0.f, aL2 = 0.f, aL3 = 0.f;
  float aH0 = 0.f, aH1 = 0.f, aH2 = 0.f, aH3 = 0.f;

  if constexpr (CH <= 32) {
    int half = lane >> 5, c = lane & 31;
    bool act = c < CH;
    int idx = s;
    for (; idx + 7 < e; idx += 8) {
      int e0 = col[idx + half], e1 = col[idx + half + 2];
      int e2 = col[idx + half + 4], e3 = col[idx + half + 6];
      if (act) {
        uint4 v0 = src[(size_t)e0 * CH + c];
        uint4 v1 = src[(size_t)e1 * CH + c];
        uint4 v2 = src[(size_t)e2 * CH + c];
        uint4 v3 = src[(size_t)e3 * CH + c];
        aL0 += (bflo(v0.x) + bflo(v1.x)) + (bflo(v2.x) + bflo(v3.x));
        aH0 += (bfhi(v0.x) + bfhi(v1.x)) + (bfhi(v2.x) + bfhi(v3.x));
        aL1 += (bflo(v0.y) + bflo(v1.y)) + (bflo(v2.y) + bflo(v3.y));
        aH1 += (bfhi(v0.y) + bfhi(v1.y)) + (bfhi(v2.y) + bfhi(v3.y));
        aL2 += (bflo(v0.z) + bflo(v1.z)) + (bflo(v2.z) + bflo(v3.z));
        aH2 += (bfhi(v0.z) + bfhi(v1.z)) + (bfhi(v2.z) + bfhi(v3.z));
        aL3 += (bflo(v0.w) + bflo(v1.w)) + (bflo(v2.w) + bflo(v3.w));
        aH3 += (bfhi(v0.w) + bfhi(v1.w)) + (bfhi(v2.w) + bfhi(v3.w));
      }
    }
    for (; idx + 1 < e; idx += 2) {
      int e0 = col[idx + half];
      if (act) {
        uint4 v = src[(size_t)e0 * CH + c];
        aL0 += bflo(v.x); aH0 += bfhi(v.x);
        aL1 += bflo(v.y); aH1 += bfhi(v.y);
        aL2 += bflo(v.z); aH2 += bfhi(v.z);
        aL3 += bflo(v.w); aH3 += bfhi(v.w);
      }
    }
    if (idx < e && half == 0 && act) {
      uint4 v = src[(size_t)col[idx] * CH + c];
      aL0 += bflo(v.x); aH0 += bfhi(v.x);
      aL1 += bflo(v.y); aH1 += bfhi(v.y);
      aL2 += bflo(v.z); aH2 += bfhi(v.z);
      aL3 += bflo(v.w); aH3 += bfhi(v.w);
    }
    aL0 += __shfl_xor(aL0, 32); aH0 += __shfl_xor(aH0, 32);
    aL1 += __shfl_xor(aL1, 32); aH1 += __shfl_xor(aH1, 32);
    aL2 += __shfl_xor(aL2, 32); aH2 += __shfl_xor(aH2, 32);
    aL3 += __shfl_xor(aL3, 32); aH3 += __shfl_xor(aH3, 32);
    float inv = deginv[wid];
    if (half == 0 && act) {
      uint4 o;
      o.x = packbf(aL0 * inv, aH0 * inv);
      o.y = packbf(aL1 * inv, aH1 * inv);
      o.z = packbf(aL2 * inv, aH2 * inv);
      o.w = packbf(aL3 * inv, aH3 * inv);
      dst[(size_t)wid * CH + c] = o;
    }
  } else {
    int c = lane;
    bool act = c < CH;
    int idx = s;
    for (; idx + 3 < e; idx += 4) {
      int e0 = col[idx], e1 = col[idx + 1], e2 = col[idx + 2], e3 = col[idx + 3];
      if (act) {
        uint4 v0 = src[(size_t)e0 * CH + c];
        uint4 v1 = src[(size_t)e1 * CH + c];
        uint4 v2 = src[(size_t)e2 * CH + c];
        uint4 v3 = src[(size_t)e3 * CH + c];
        aL0 += (bflo(v0.x) + bflo(v1.x)) + (bflo(v2.x) + bflo(v3.x));
        aH0 += (bfhi(v0.x) + bfhi(v1.x)) + (bfhi(v2.x) + bfhi(v3.x));
        aL1 += (bflo(v0.y) + bflo(v1.y)) + (bflo(v2.y) + bflo(v3.y));
        aH1 += (bfhi(v0.y) + bfhi(v1.y)) + (bfhi(v2.y) + bfhi(v3.y));
        aL2 += (bflo(v0.z) + bflo(v1.z)) + (bflo(v2.z) + bflo(v3.z));
        aH2 += (bfhi(v0.z) + bfhi(v1.z)) + (bfhi(v2.z) + bfhi(v3.z));
        aL3 += (bflo(v0.w) + bflo(v1.w)) + (bflo(v2.w) + bflo(v3.w));
        aH3 += (bfhi(v0.w) + bfhi(v1.w)) + (bfhi(v2.w) + bfhi(v3.w));
      }
    }
    for (; idx < e; ++idx) {
      int e0 = col[idx];
      if (act) {
        uint4 v = src[(size_t)e0 * CH + c];
        aL0 += bflo(v.x); aH0 += bfhi(v.x);
        aL1 += bflo(v.y); aH1 += bfhi(v.y);
        aL2 += bflo(v.z); aH2 += bfhi(v.z);
        aL3 += bflo(v.w); aH3 += bfhi(v.w);
      }
    }
    float inv = deginv[wid];
    if (act) {
      uint4 o;
      o.x = packbf(aL0 * inv, aH0 * inv);
      o.y = packbf(aL1 * inv, aH1 * inv);
      o.z = packbf(aL2 * inv, aH2 * inv);
      o.w = packbf(aL3 * inv, aH3 * inv);
      dst[(size_t)wid * CH + c] = o;
    }
  }
}

// ---------------- combine (MFMA) — standalone-hop inputs + in-block BN affine -----------------
template <int TIN, int TOUT>
__global__ __launch_bounds__(256, 4) void k_combine(const uint32* __restrict__ h,
    const uint32* __restrict__ c1, const uint32* __restrict__ c2, const uint32* __restrict__ c3,
    const uint32* __restrict__ bpack, const float* __restrict__ gcb,
    const uint32* __restrict__ xcur, int layer,
    const float* __restrict__ bng, const float* __restrict__ bnb,
    uint32* __restrict__ xnext, float* __restrict__ sums) {
  constexpr int RS = 34;
  __shared__ float xst[128 * RS];
  __shared__ float pbuf[96];        // gcb(32), sc(32), sh(32)
  __shared__ float red[256];
  __shared__ float r1s[32], r2s[32];
  int tid = threadIdx.x;
  int nrows = N * TOUT;
  int base = blockIdx.x * 128;
  int wave = tid >> 6, lane = tid & 63;
  int m = lane & 15, q = lane >> 4;
  if (tid < 32) {
    pbuf[tid] = gcb[layer * 32 + tid];
    r1s[tid] = 0.0f; r2s[tid] = 0.0f;
  }

  // ---- BN affine of previous layer (identity at layer 0) ----
  if (layer == 0) {
    if (tid < 64) pbuf[32 + tid] = (tid < 32) ? 1.0f : 0.0f;
  } else {
    const float* lp = sums + (size_t)(layer - 1) * NPART * 64;
    int o = tid & 63, grp = tid >> 6;
    float t1 = 0.f;
    for (int p = grp; p < NPART; p += 4) t1 += lp[p * 64 + o];
    red[grp * 64 + o] = t1;
    __syncthreads();
    if (tid < 64) red[tid] = red[tid] + red[64 + tid] + red[128 + tid] + red[192 + tid];
    __syncthreads();
    if (tid < 32) {
      float cnt = (float)N * (float)TIN;
      float mu = red[tid] / cnt;
      float var = red[32 + tid] / cnt - mu * mu;
      float sc = bng[(layer - 1) * 32 + tid] * rsqrtf(var + 1e-5f);
      pbuf[32 + tid] = sc;
      pbuf[64 + tid] = bnb[(layer - 1) * 32 + tid] - mu * sc;
    }
  }

  const uint32* bp = bpack + (size_t)layer * 2048;
  short8 bf[4][2];
#pragma unroll
  for (int s = 0; s < 4; s++)
#pragma unroll
    for (int hh = 0; hh < 2; hh++)
      bf[s][hh] = *(const short8*)(bp + (size_t)((s * 2 + hh) * 64 + lane) * 4);

  f32x4 acc[2][2] = {{{0.f,0.f,0.f,0.f},{0.f,0.f,0.f,0.f}},{{0.f,0.f,0.f,0.f},{0.f,0.f,0.f,0.f}}};
  const uint32* srcs[4] = { h, c1, c2, c3 };
#pragma unroll
  for (int s = 0; s < 4; s++) {
    const uint32* sp = srcs[s];
#pragma unroll
    for (int t = 0; t < 2; t++) {
      int row = base + wave * 32 + t * 16 + m;
      short8 af = {0,0,0,0,0,0,0,0};
      if (row < nrows) af = *(const short8*)(sp + (size_t)row * 16 + q * 4);
      acc[t][0] = __builtin_amdgcn_mfma_f32_16x16x32_bf16(af, bf[s][0], acc[t][0], 0, 0, 0);
      acc[t][1] = __builtin_amdgcn_mfma_f32_16x16x32_bf16(af, bf[s][1], acc[t][1], 0, 0, 0);
    }
  }

  __syncthreads();
#pragma unroll
  for (int t = 0; t < 2; t++)
#pragma unroll
    for (int hh = 0; hh < 2; hh++)
#pragma unroll
      for (int r = 0; r < 4; r++)
        xst[(wave * 32 + t * 16 + q * 4 + r) * RS + hh * 16 + m] = acc[t][hh][r];
  __syncthreads();

  constexpr int toff = TIN - TOUT;
  int rg = tid >> 3, oq = tid & 7;
  float gb0 = pbuf[oq * 4 + 0], gb1 = pbuf[oq * 4 + 1], gb2 = pbuf[oq * 4 + 2], gb3 = pbuf[oq * 4 + 3];
  float sc0 = pbuf[32 + oq * 4 + 0], sc1 = pbuf[32 + oq * 4 + 1], sc2 = pbuf[32 + oq * 4 + 2], sc3 = pbuf[32 + oq * 4 + 3];
  float sh0 = pbuf[64 + oq * 4 + 0], sh1 = pbuf[64 + oq * 4 + 1], sh2 = pbuf[64 + oq * 4 + 2], sh3 = pbuf[64 + oq * 4 + 3];
  float s1[4] = {0.f, 0.f, 0.f, 0.f}, s2[4] = {0.f, 0.f, 0.f, 0.f};
#pragma unroll
  for (int i = 0; i < 4; i++) {
    int r = rg + 32 * i;
    int row = base + r;
    bool act = row < nrows;
    float2 aa = *(const float2*)&xst[r * RS + oq * 4];
    float2 ab = *(const float2*)&xst[r * RS + oq * 4 + 2];
    float xr0 = 0.f, xr1 = 0.f, xr2 = 0.f, xr3 = 0.f;
    if (act) {
      int node = row / TOUT, t_ = row - node * TOUT;
      const uint32* rp = xcur + ((size_t)node * TIN + toff + t_) * 16 + oq * 2;
      uint32 va = rp[0], vb = rp[1];
      xr0 = bflo(va); xr1 = bfhi(va); xr2 = bflo(vb); xr3 = bfhi(vb);
    }
    float v0 = aa.x + gb0 + sc0 * xr0 + sh0;
    float v1 = aa.y + gb1 + sc1 * xr1 + sh1;
    float v2 = ab.x + gb2 + sc2 * xr2 + sh2;
    float v3 = ab.y + gb3 + sc3 * xr3 + sh3;
    *(float2*)&xst[r * RS + oq * 4]     = make_float2(v0, v1);
    *(float2*)&xst[r * RS + oq * 4 + 2] = make_float2(v2, v3);
    if (act) {
      s1[0] += v0; s1[1] += v1; s1[2] += v2; s1[3] += v3;
      s2[0] += v0 * v0; s2[1] += v1 * v1; s2[2] += v2 * v2; s2[3] += v3 * v3;
    }
  }
#pragma unroll
  for (int j = 0; j < 4; j++) {
    atomicAdd(&r1s[oq * 4 + j], s1[j]);
    atomicAdd(&r2s[oq * 4 + j], s2[j]);
  }
  __syncthreads();

  {
    uint2* outp = (uint2*)xnext;
#pragma unroll
    for (int it = 0; it < 4; it++) {
      int l = it * 256 + tid;
      int g = base * 8 + l;
      if (g < nrows * 8) {
        int rl = l >> 3, j4 = l & 7;
        float2 a = *(const float2*)&xst[rl * RS + j4 * 4];
        float2 b = *(const float2*)&xst[rl * RS + j4 * 4 + 2];
        outp[g] = make_uint2(packbf(a.x, a.y), packbf(b.x, b.y));
      }
    }
  }
  // BN partial atomics spread over NPART buffers: sums[(layer*NPART+part)*64 + j]
  {
    int part = blockIdx.x & (NPART - 1);
    float* sp = sums + ((size_t)layer * NPART + part) * 64;
    if (tid < 32) atomicAdd(&sp[tid], r1s[tid]);
    else if (tid < 64) atomicAdd(&sp[tid], r2s[tid - 32]);
  }
}

// ---------------- head GEMM 1: S = relu(HLbf @ WS2^T + SB), bf16 in, bf16 out ----------------
__global__ __launch_bounds__(256) void k_gemm1(const uint32* __restrict__ A,
    const uint32* __restrict__ bp, const float* __restrict__ bias, uint32* __restrict__ Sb) {
  constexpr int RS = 68;
  __shared__ float xst[128 * RS];
  int tid = threadIdx.x;
  int wave = tid >> 6, lane = tid & 63;
  int m = lane & 15, q = lane >> 4;
  int base = blockIdx.x * 128;
  int ot0 = blockIdx.y * 8;

  f32x4 acc[2][8];
#pragma unroll
  for (int t = 0; t < 2; t++)
#pragma unroll
    for (int nt = 0; nt < 8; nt++) acc[t][nt] = (f32x4){0.f, 0.f, 0.f, 0.f};

  int row0 = base + wave * 32 + m;
  int row1 = row0 + 16;
#pragma unroll 1
  for (int ks = 0; ks < 8; ks++) {
    short8 a0 = {0,0,0,0,0,0,0,0}, a1 = {0,0,0,0,0,0,0,0};
    if (row0 < N) a0 = *(const short8*)(A + (size_t)row0 * 128 + ks * 16 + q * 4);
    if (row1 < N) a1 = *(const short8*)(A + (size_t)row1 * 128 + ks * 16 + q * 4);
#pragma unroll
    for (int nt = 0; nt < 8; nt++) {
      short8 b = *(const short8*)(bp + (size_t)(((ot0 + nt) * 8 + ks) * 64 + lane) * 4);
      acc[0][nt] = __builtin_amdgcn_mfma_f32_16x16x32_bf16(a0, b, acc[0][nt], 0, 0, 0);
      acc[1][nt] = __builtin_amdgcn_mfma_f32_16x16x32_bf16(a1, b, acc[1][nt], 0, 0, 0);
    }
  }

#pragma unroll
  for (int half = 0; half < 2; half++) {
    if (half) __syncthreads();
#pragma unroll
    for (int t = 0; t < 2; t++)
#pragma unroll
      for (int nn = 0; nn < 4; nn++) {
        float bv = bias[blockIdx.y * 128 + (half * 4 + nn) * 16 + m];
#pragma unroll
        for (int r = 0; r < 4; r++) {
          float v = acc[t][half * 4 + nn][r] + bv;
          xst[(wave * 32 + t * 16 + q * 4 + r) * RS + nn * 16 + m] = fmaxf(v, 0.0f);
        }
      }
    __syncthreads();
#pragma unroll
    for (int it = 0; it < 8; it++) {
      int l = it * 256 + tid;
      int rl = l >> 4, c4 = l & 15;
      int grow = base + rl;
      if (grow < N) {
        float2 a = *(const float2*)&xst[rl * RS + c4 * 4];
        float2 b = *(const float2*)&xst[rl * RS + c4 * 4 + 2];
        *(uint2*)(Sb + (size_t)grow * 128 + blockIdx.y * 64 + half * 32 + c4 * 2) =
            make_uint2(packbf(a.x, a.y), packbf(b.x, b.y));
      }
    }
  }
}

// ---------------- head GEMM 2 fused: out += relu(Sbf @ out1_w^T + b1) @ out2_w^T (+ b2) --------
__global__ __launch_bounds__(256) void k_gemm2f(const uint32* __restrict__ A,
    const uint32* __restrict__ bp, const float* __restrict__ bias,
    const uint32* __restrict__ w2p, const float* __restrict__ b2, float* __restrict__ out) {
  constexpr int RS = 68;
  __shared__ float xst[128 * RS];
  int tid = threadIdx.x;
  int wave = tid >> 6, lane = tid & 63;
  int m = lane & 15, q = lane >> 4;
  int base = blockIdx.x * 128;
  int ot0 = blockIdx.y * 8;

  f32x4 acc[2][8];
#pragma unroll
  for (int t = 0; t < 2; t++)
#pragma unroll
    for (int nt = 0; nt < 8; nt++) acc[t][nt] = (f32x4){0.f, 0.f, 0.f, 0.f};

  int row0 = base + wave * 32 + m;
  int row1 = row0 + 16;
#pragma unroll 1
  for (int ks = 0; ks < 8; ks++) {
    short8 a0 = {0,0,0,0,0,0,0,0}, a1 = {0,0,0,0,0,0,0,0};
    if (row0 < N) a0 = *(const short8*)(A + (size_t)row0 * 128 + ks * 16 + q * 4);
    if (row1 < N) a1 = *(const short8*)(A + (size_t)row1 * 128 + ks * 16 + q * 4);
#pragma unroll
    for (int nt = 0; nt < 8; nt++) {
      short8 b = *(const short8*)(bp + (size_t)(((ot0 + nt) * 8 + ks) * 64 + lane) * 4);
      acc[0][nt] = __builtin_amdgcn_mfma_f32_16x16x32_bf16(a0, b, acc[0][nt], 0, 0, 0);
      acc[1][nt] = __builtin_amdgcn_mfma_f32_16x16x32_bf16(a1, b, acc[1][nt], 0, 0, 0);
    }
  }

  f32x4 acc2[2][2];
#pragma unroll
  for (int t = 0; t < 2; t++)
#pragma unroll
    for (int o2 = 0; o2 < 2; o2++) acc2[t][o2] = (f32x4){0.f, 0.f, 0.f, 0.f};

#pragma unroll
  for (int half = 0; half < 2; half++) {
    if (half) __syncthreads();
#pragma unroll
    for (int t = 0; t < 2; t++)
#pragma unroll
      for (int nn = 0; nn < 4; nn++) {
        float bv = bias[blockIdx.y * 128 + (half * 4 + nn) * 16 + m];
#pragma unroll
        for (int r = 0; r < 4; r++) {
          float v = acc[t][half * 4 + nn][r] + bv;
          xst[(wave * 32 + t * 16 + q * 4 + r) * RS + nn * 16 + m] = fmaxf(v, 0.0f);
        }
      }
    __syncthreads();
#pragma unroll
    for (int kl = 0; kl < 2; kl++) {
      short8 a2[2];
#pragma unroll
      for (int t = 0; t < 2; t++) {
        const float* xp = &xst[(size_t)(wave * 32 + t * 16 + m) * RS + kl * 32 + q * 8];
        float4 f0 = *(const float4*)xp;
        float4 f1 = *(const float4*)(xp + 4);
        uint32 u[4];
        u[0] = packbf(f0.x, f0.y); u[1] = packbf(f0.z, f0.w);
        u[2] = packbf(f1.x, f1.y); u[3] = packbf(f1.z, f1.w);
        a2[t] = *(const short8*)u;
      }
      int ksg = blockIdx.y * 4 + half * 2 + kl;
#pragma unroll
      for (int o2 = 0; o2 < 2; o2++) {
        short8 b = *(const short8*)(w2p + (size_t)(((o2 * 16 + ksg) * 64 + lane) * 4));
        acc2[0][o2] = __builtin_amdgcn_mfma_f32_16x16x32_bf16(a2[0], b, acc2[0][o2], 0, 0, 0);
        acc2[1][o2] = __builtin_amdgcn_mfma_f32_16x16x32_bf16(a2[1], b, acc2[1][o2], 0, 0, 0);
      }
    }
  }

#pragma unroll
  for (int t = 0; t < 2; t++)
#pragma unroll
    for (int o2 = 0; o2 < 2; o2++) {
      int oc = o2 * 16 + m;
      if (oc < 24) {
#pragma unroll
        for (int r = 0; r < 4; r++) {
          int row = base + wave * 32 + t * 16 + q * 4 + r;
          if (row < N) {
            float v = acc2[t][o2][r];
            if (blockIdx.y == 0) v += b2[oc];
            atomicAdd(&out[(size_t)row * 24 + oc], v);
          }
        }
      }
    }
}

// ---------------- host side ----------------
struct Ptrs {
  const float *fw, *fb, *gw, *gb, *gcb, *bng, *bnb;
  const uint32 *bpack;
  void *H, *C1, *C2, *C3;
  uint32 *HL;
  float *sums;
  const int *row, *col;
  const float *deg;
};

template <int TIN, int TOUT, int D, bool LAST>
static void run_layer(int layer, const Ptrs& P, uint32*& xc, uint32*& xn, hipStream_t stream) {
  int cblocks = (N * TOUT + 127) / 128;
  k_conv<TIN, TOUT, D, LAST><<<cblocks, 256, 0, stream>>>(xc, P.fw, P.fb, P.gw, P.gb,
                                                          P.sums, P.bng, P.bnb, layer,
                                                          (uint32*)P.H, P.HL);
  if (!LAST) {
    constexpr int CH = TOUT * 4;   // uint4 chunks per row
    int hb = (N * 64 + 255) / 256;
    k_hop<CH><<<hb, 256, 0, stream>>>((const uint32*)P.H, (uint32*)P.C1, P.row, P.col, P.deg);
    k_hop<CH><<<hb, 256, 0, stream>>>((const uint32*)P.C1, (uint32*)P.C2, P.row, P.col, P.deg);
    k_hop<CH><<<hb, 256, 0, stream>>>((const uint32*)P.C2, (uint32*)P.C3, P.row, P.col, P.deg);
    k_combine<TIN, TOUT><<<cblocks, 256, 0, stream>>>((const uint32*)P.H, (const uint32*)P.C1,
                                                      (const uint32*)P.C2, (const uint32*)P.C3,
                                                      P.bpack, P.gcb, xc, layer,
                                                      P.bng, P.bnb, xn, P.sums);
    uint32* tmp = xc; xc = xn; xn = tmp;
  }
}

extern "C" void kernel_launch(void* const* d_in, const int* in_sizes, int n_in,
                              void* d_out, int out_size, void* d_ws, size_t ws_size,
                              hipStream_t stream) {
  const float* inputs  = (const float*)d_in[0];
  const int*   esrc    = (const int*)d_in[1];
  const int*   edst    = (const int*)d_in[2];
  const float* enter_w = (const float*)d_in[3];
  const float* enter_b = (const float*)d_in[4];
  const float* filt_w  = (const float*)d_in[5];
  const float* filt_b  = (const float*)d_in[6];
  const float* gate_w  = (const float*)d_in[7];
  const float* gate_b  = (const float*)d_in[8];
  const float* gc_w    = (const float*)d_in[9];
  const float* gc_b    = (const float*)d_in[10];
  const float* skip_w  = (const float*)d_in[11];
  const float* skip_b  = (const float*)d_in[12];
  const float* bn_g    = (const float*)d_in[13];
  const float* bn_b    = (const float*)d_in[14];
  const float* out1_w  = (const float*)d_in[15];
  const float* out1_b  = (const float*)d_in[16];
  const float* out2_w  = (const float*)d_in[17];
  const float* out2_b  = (const float*)d_in[18];

  char* ws = (char*)d_ws;
  uint32* XA = (uint32*)(ws + XA_OFF);
  uint32* XB = (uint32*)(ws + XB_OFF);
  void* H    = (void*)(ws + H_OFF);
  void* C1   = (void*)(ws + C1_OFF);
  void* C2   = (void*)(ws + C2_OFF);
  void* C3   = (void*)(ws + C3_OFF);
  uint32* HLB = (uint32*)(ws + HL_OFF);     // bf16 [N][128]
  uint32* W2P = (uint32*)(ws + W2P_OFF);
  float* SB  = (float*)(ws + SB_OFF);
  float* SUMS = (float*)(ws + SUMS_OFF);
  int* CNT  = (int*)(ws + CNT_OFF);
  int* ROW  = (int*)(ws + ROW_OFF);
  int* FILL = (int*)(ws + FILL_OFF);
  int* COL  = (int*)(ws + COL_OFF);
  float* DEG = (float*)(ws + DEG_OFF);
  uint32* BP = (uint32*)(ws + BP_OFF);
  uint32* BW1 = (uint32*)(ws + BW1_OFF);
  uint32* BW2 = (uint32*)(ws + BW2_OFF);
  int* BS = (int*)(ws + BS_OFF);
  uint32* Sb  = (uint32*)(ws + S_OFF);      // bf16 S [N][128]

  // one mega-setup launch: zeros (CNT/SUMS/d_out), all weight packs, enter conv
  k_setup<<<SU_EN1, 256, 0, stream>>>(inputs, enter_w, enter_b,
                                      gc_w, skip_w, skip_b, out1_w, out2_w,
                                      CNT, SUMS, (float*)d_out, out_size,
                                      BP, BW1, BW2, W2P, SB, XA);

  k_count<<<(E + 255) / 256, 256, 0, stream>>>(edst, CNT);
  k_scan1<<<NB_SCAN, 256, 0, stream>>>(CNT, BS);
  k_scan3<<<NB_SCAN, 256, 0, stream>>>(CNT, BS, ROW, FILL, DEG);
  k_scatter<<<(E + 255) / 256, 256, 0, stream>>>(esrc, edst, FILL, COL);

  Ptrs P;
  P.fw = filt_w; P.fb = filt_b; P.gw = gate_w; P.gb = gate_b;
  P.gcb = gc_b; P.bng = bn_g; P.bnb = bn_b; P.bpack = BP;
  P.H = H; P.C1 = C1; P.C2 = C2; P.C3 = C3; P.HL = HLB; P.sums = SUMS;
  P.row = ROW; P.col = COL; P.deg = DEG;

  uint32* xc = XA; uint32* xn = XB;
  run_layer<13, 12, 1, false>(0, P, xc, xn, stream);
  run_layer<12, 10, 2, false>(1, P, xc, xn, stream);
  run_layer<10, 9, 1, false>(2, P, xc, xn, stream);
  run_layer<9, 7, 2, false>(3, P, xc, xn, stream);
  run_layer<7, 6, 1, false>(4, P, xc, xn, stream);
  run_layer<6, 4, 2, false>(5, P, xc, xn, stream);
  run_layer<4, 3, 1, false>(6, P, xc, xn, stream);
  run_layer<3, 1, 2, true>(7, P, xc, xn, stream);

  // head: S = relu(HL @ WS2^T + SB) [bf16]; out = relu(S @ out1_w^T + b1) @ out2_w^T + b2 (fused)
  dim3 g1((N + 127) / 128, 2);
  k_gemm1<<<g1, 256, 0, stream>>>(HLB, BW1, SB, Sb);
  dim3 g2((N + 127) / 128, 4);
  k_gemm2f<<<g2, 256, 0, stream>>>(Sb, BW2, out1_b, W2P, out2_b, (float*)d_out);
}

// Round 10
// 957.030 us; speedup vs baseline: 1.2395x; 1.1547x over previous
//
#include <hip/hip_runtime.h>
#include <cmath>

// ---------------- problem constants ----------------
constexpr int N = 20000, T = 13, E = 320000;
constexpr int NB_SCAN = (N + 255) / 256;   // 79
constexpr int NPART = 64;                  // BN-sum partial buffers (atomic contention spread)
typedef unsigned int uint32;

typedef __attribute__((ext_vector_type(8))) short short8;   // 8 bf16 = 4 VGPRs
typedef __attribute__((ext_vector_type(4))) float f32x4;    // MFMA C/D frag

// ---------------- bf16 helpers ----------------
__device__ __forceinline__ unsigned short f2bf(float f) {
  unsigned int u = __float_as_uint(f);
  unsigned int r = (u + 0x7FFFu + ((u >> 16) & 1u)) >> 16;
  return (unsigned short)r;
}
__device__ __forceinline__ float bflo(uint32 v) { return __uint_as_float(v << 16); }
__device__ __forceinline__ float bfhi(uint32 v) { return __uint_as_float(v & 0xFFFF0000u); }
__device__ __forceinline__ uint32 packbf(float lo, float hi) {
  return (uint32)f2bf(lo) | ((uint32)f2bf(hi) << 16);
}

// ---------------- workspace layout ----------------
// Activations are node-major: row = n*T + t (proven fastest for the edge-gather hops:
// one random gather pulls a 768B contiguous row -> full cache-line utilization).
constexpr size_t WALIGN = 512;
constexpr size_t align_up(size_t x) { return (x + WALIGN - 1) & ~(WALIGN - 1); }

constexpr size_t XA_OFF  = 0;
constexpr size_t X_SZ    = align_up((size_t)N * 13 * 32 * 4);
constexpr size_t XB_OFF  = XA_OFF + X_SZ;
constexpr size_t H_OFF   = XB_OFF + X_SZ;
constexpr size_t H_SZ    = align_up((size_t)N * 12 * 32 * 4);
constexpr size_t C1_OFF  = H_OFF + H_SZ;
constexpr size_t C2_OFF  = C1_OFF + H_SZ;
constexpr size_t C3_OFF  = C2_OFF + H_SZ;
constexpr size_t HL_OFF  = C3_OFF + H_SZ;
constexpr size_t HL_SZ   = align_up((size_t)N * 256 * 4);
constexpr size_t W2P_OFF = HL_OFF + HL_SZ;                       // out2_w bf16 pack (8192 u32)
constexpr size_t SB_OFF  = W2P_OFF + align_up(8192 * 4);
constexpr size_t SUMS_OFF = SB_OFF + align_up(256 * 4);          // 8 layers x NPART x 64 floats
constexpr size_t PAR_OFF  = SUMS_OFF + align_up(8 * NPART * 64 * 4);
constexpr size_t CNT_OFF  = PAR_OFF + align_up(9 * 64 * 4);
constexpr size_t ROW_OFF  = CNT_OFF + align_up((size_t)N * 4);
constexpr size_t FILL_OFF = ROW_OFF + align_up((size_t)(N + 1) * 4);
constexpr size_t COL_OFF  = FILL_OFF + align_up((size_t)N * 4);
constexpr size_t DEG_OFF  = COL_OFF + align_up((size_t)E * 4);
constexpr size_t BP_OFF   = DEG_OFF + align_up((size_t)N * 4);   // gc_w B-frag pack
constexpr size_t CP_OFF   = BP_OFF + align_up(8 * 2048 * 4);     // conv W-frag pack
constexpr size_t BW1_OFF  = CP_OFF + align_up(8 * 2176 * 4);     // skip_w B-frag pack (O=256)
constexpr size_t BW2_OFF  = BW1_OFF + align_up(32768 * 4);       // out1_w B-frag pack (O=512)
constexpr size_t BS_OFF   = BW2_OFF + align_up(65536 * 4);       // scan partials
// aliases used after all layers are done:
constexpr size_t S_OFF  = C2_OFF;   // N*128 uint32 (bf16 S)

// ---------------- mega-setup kernel: all independent init/prep work in one launch ----------
// block ranges (each block = 256 threads)
constexpr int SU_CNT1 = 20;              // CNT zero (5000 int4)
constexpr int SU_SUM1 = SU_CNT1 + 32;    // SUMS zero (8192 float4)
constexpr int SU_OUT1 = SU_SUM1 + 469;   // d_out zero (120000 float4)
constexpr int SU_PAR1 = SU_OUT1 + 1;     // par slot0 identity
constexpr int SU_GCW1 = SU_PAR1 + 64;    // gc_w pack (16384)
constexpr int SU_BW11 = SU_GCW1 + 128;   // skip_w -> BW1 pack (32768)
constexpr int SU_BW21 = SU_BW11 + 256;   // out1_w -> BW2 pack (65536)
constexpr int SU_W21  = SU_BW21 + 32;    // out2_w -> W2P pack (8192)
constexpr int SU_SB1  = SU_W21 + 1;      // skip_b sum (256)
constexpr int SU_CV1  = SU_SB1 + 9;      // conv layer-0 pack, identity affine (2112)
constexpr int SU_EN1  = SU_CV1 + 16250;  // enter conv (4160000)

__global__ __launch_bounds__(256) void k_setup(
    const float* __restrict__ inputs, const float* __restrict__ enter_w, const float* __restrict__ enter_b,
    const float* __restrict__ filt_w, const float* __restrict__ filt_b,
    const float* __restrict__ gate_w, const float* __restrict__ gate_b,
    const float* __restrict__ gc_w, const float* __restrict__ skip_w, const float* __restrict__ skip_b,
    const float* __restrict__ out1_w, const float* __restrict__ out2_w,
    int* __restrict__ cnt, float* __restrict__ sums,
    float* __restrict__ dout, int out_sz,
    float* __restrict__ par, uint32* __restrict__ bp, uint32* __restrict__ bw1,
    uint32* __restrict__ bw2, uint32* __restrict__ w2p, float* __restrict__ sbias,
    uint32* __restrict__ cpack, uint32* __restrict__ x) {
  int b = blockIdx.x, tid = threadIdx.x;
  if (b < SU_CNT1) {
    int i = b * 256 + tid;
    if (i < 5000) ((int4*)cnt)[i] = make_int4(0, 0, 0, 0);
  } else if (b < SU_SUM1) {
    int i = (b - SU_CNT1) * 256 + tid;
    if (i < 8192) ((float4*)sums)[i] = make_float4(0.f, 0.f, 0.f, 0.f);
  } else if (b < SU_OUT1) {
    int i = (b - SU_SUM1) * 256 + tid;
    if (i < (out_sz >> 2)) ((float4*)dout)[i] = make_float4(0.f, 0.f, 0.f, 0.f);
  } else if (b < SU_PAR1) {
    if (tid < 64) par[tid] = (tid < 32) ? 1.0f : 0.0f;
  } else if (b < SU_GCW1) {
    int idx = (b - SU_PAR1) * 256 + tid;   // < 16384 exact
    int w4 = idx & 3, lane = (idx >> 2) & 63, hh = (idx >> 8) & 1, s = (idx >> 9) & 3, l = idx >> 11;
    int n = lane & 15, q = lane >> 4;
    int k0 = q * 8 + w4 * 2, o = hh * 16 + n;
    const float* g = gc_w + (((size_t)(l * 4 + s) * 32 + k0) * 32 + o);
    bp[idx] = packbf(g[0], g[32]);
  } else if (b < SU_BW11) {
    int idx = (b - SU_GCW1) * 256 + tid;   // < 32768 exact
    int w4 = idx & 3, lane = (idx >> 2) & 63, ks = (idx >> 8) & 7, ot = idx >> 11;
    int n = lane & 15, q = lane >> 4;
    int c = q * 8 + w4 * 2, o = ot * 16 + n;
    const float* wr = skip_w + ((size_t)ks * 256 + o) * 32 + c;
    bw1[idx] = packbf(wr[0], wr[1]);
  } else if (b < SU_BW21) {
    int idx = (b - SU_BW11) * 256 + tid;   // < 65536 exact
    int w4 = idx & 3, lane = (idx >> 2) & 63, ks = (idx >> 8) & 7, ot = idx >> 11;
    int n = lane & 15, q = lane >> 4;
    int k = ks * 32 + q * 8 + w4 * 2;
    const float* wr = out1_w + (size_t)(ot * 16 + n) * 256 + k;
    bw2[idx] = packbf(wr[0], wr[1]);
  } else if (b < SU_W21) {
    int idx = (b - SU_BW21) * 256 + tid;   // < 8192 exact
    int w4 = idx & 3, lane = (idx >> 2) & 63, ks = (idx >> 8) & 15, ot = idx >> 12;
    int n = lane & 15, q = lane >> 4;
    int k = ks * 32 + q * 8 + w4 * 2;
    int o = ot * 16 + n;
    float v0 = 0.0f, v1 = 0.0f;
    if (o < 24) { const float* wr = out2_w + (size_t)o * 512 + k; v0 = wr[0]; v1 = wr[1]; }
    w2p[idx] = packbf(v0, v1);
  } else if (b < SU_SB1) {
    float s = 0.0f;
    for (int l = 0; l < 8; l++) s += skip_b[l * 256 + tid];
    sbias[tid] = s;
  } else if (b < SU_CV1) {
    int i = (b - SU_SB1) * 256 + tid;
    if (i < 2048) {
      int w4 = i & 3, lane = (i >> 2) & 63, hh = (i >> 8) & 1, ktap = (i >> 9) & 1, sel = i >> 10;
      int n = lane & 15, q = lane >> 4;
      int c0 = q * 8 + w4 * 2, o = hh * 16 + n;
      const float* w = sel ? gate_w : filt_w;
      float v0 = w[((size_t)o * 32 + c0) * 2 + ktap];
      float v1 = w[((size_t)o * 32 + c0 + 1) * 2 + ktap];
      cpack[i] = packbf(v0, v1);
    } else if (i < 2112) {
      int j = i - 2048; int sel = j >> 5; int o = j & 31;
      ((float*)cpack)[2048 + j] = sel ? gate_b[o] : filt_b[o];
    }
  } else {
    int idx = (b - SU_CV1) * 256 + tid;    // < 4160000 exact
    int cw = idx & 15; int tmp = idx >> 4; int t = tmp % 13; int n = tmp / 13;
    int c0 = cw * 2;
    const float* ip = inputs + (size_t)n * (13 * 3) + t * 3;
    float v0 = enter_b[c0]     + enter_w[c0 * 3 + 0]       * ip[0] + enter_w[c0 * 3 + 1]       * ip[1] + enter_w[c0 * 3 + 2]       * ip[2];
    float v1 = enter_b[c0 + 1] + enter_w[(c0 + 1) * 3 + 0] * ip[0] + enter_w[(c0 + 1) * 3 + 1] * ip[1] + enter_w[(c0 + 1) * 3 + 2] * ip[2];
    x[idx] = packbf(v0, v1);
  }
}

// ---------------- CSR build ----------------
__global__ void k_count(const int* __restrict__ dst, int* __restrict__ cnt) {
  int i = blockIdx.x * 256 + threadIdx.x;
  if (i < E) atomicAdd(&cnt[dst[i]], 1);
}

// parallel scan, phase 1: per-block sums
__global__ __launch_bounds__(256) void k_scan1(const int* __restrict__ cnt, int* __restrict__ bsum) {
  __shared__ int sc[256];
  int t = threadIdx.x; int idx = blockIdx.x * 256 + t;
  int v = (idx < N) ? cnt[idx] : 0;
  sc[t] = v; __syncthreads();
  for (int off = 1; off < 256; off <<= 1) {
    int u = (t >= off) ? sc[t - off] : 0;
    __syncthreads();
    sc[t] += u;
    __syncthreads();
  }
  if (t == 255) bsum[blockIdx.x] = sc[255];
}

// phase 2 (merged): each block redundantly scans bsum in LDS, then per-element scan
__global__ __launch_bounds__(256) void k_scan3(const int* __restrict__ cnt, const int* __restrict__ bsum,
                                               int* __restrict__ rowptr, int* __restrict__ fill,
                                               float* __restrict__ deginv) {
  __shared__ int sc[256];
  __shared__ int bo[128];
  int t = threadIdx.x; int idx = blockIdx.x * 256 + t;
  if (t < 128) bo[t] = (t < NB_SCAN) ? bsum[t] : 0;
  int v = (idx < N) ? cnt[idx] : 0;
  sc[t] = v; __syncthreads();
  for (int off = 1; off < 128; off <<= 1) {
    int u1 = (t < 128 && t >= off) ? bo[t - off] : 0;
    int u2 = (t >= off) ? sc[t - off] : 0;
    __syncthreads();
    if (t < 128) bo[t] += u1;
    sc[t] += u2;
    __syncthreads();
  }
  // one more step for sc (needs 256 wide; bo only needs 128)
  {
    int u2 = (t >= 128) ? sc[t - 128] : 0;
    __syncthreads();
    sc[t] += u2;
    __syncthreads();
  }
  if (idx < N) {
    int myoff = bo[blockIdx.x] - bsum[blockIdx.x];   // exclusive offset of this block
    int run = myoff + sc[t] - v;
    rowptr[idx] = run; fill[idx] = run;
    deginv[idx] = 1.0f / (float)(v > 1 ? v : 1);
  }
  if (blockIdx.x == 0 && t == 0) rowptr[N] = bo[NB_SCAN - 1];
}

__global__ void k_scatter(const int* __restrict__ src, const int* __restrict__ dst,
                          int* __restrict__ fill, int* __restrict__ col) {
  int i = blockIdx.x * 256 + threadIdx.x;
  if (i < E) { int d = dst[i]; int p = atomicAdd(&fill[d], 1); col[p] = src[i]; }
}

// ---------------- gated dilated conv (MFMA) — round-15 proven form, node-major --------------
// hlast is a bf16 buffer: [node][128] uint32, slice layer*16 + j.
// LAST=true: h buffer is dead after this layer (no hops/combine) -> skip the h store.
template <int TIN, int TOUT, int D, bool LAST>
__global__ __launch_bounds__(256, 4) void k_conv(const uint32* __restrict__ x,
    const uint32* __restrict__ cpbuf, int layer,
    uint32* __restrict__ h, uint32* __restrict__ hlast) {
  constexpr int RS = 34;
  __shared__ float xst[128 * RS];
  int tid = threadIdx.x;
  int wave = tid >> 6, lane = tid & 63;
  int m = lane & 15, q = lane >> 4;
  int nrows = N * TOUT;
  int base = blockIdx.x * 128;

  const uint32* cp = cpbuf + (size_t)layer * 2176;
  short8 bf[2][2][2];   // [sel][ktap][hh]
#pragma unroll
  for (int sel = 0; sel < 2; sel++)
#pragma unroll
    for (int kt = 0; kt < 2; kt++)
#pragma unroll
      for (int hh = 0; hh < 2; hh++)
        bf[sel][kt][hh] = *(const short8*)(cp + (size_t)(((sel * 2 + kt) * 2 + hh) * 64 + lane) * 4);
  const float* bias = (const float*)(cp + 2048);
  float fb0 = bias[m], fb1 = bias[16 + m], gb0 = bias[32 + m], gb1 = bias[48 + m];

#pragma unroll
  for (int tile = 0; tile < 2; tile++) {
    int row = base + wave * 32 + tile * 16 + m;
    bool valid = row < nrows;
    int rr = valid ? row : 0;
    int n = rr / TOUT, tt = rr - n * TOUT;
    const uint32* xr = x + ((size_t)n * TIN + tt) * 16 + q * 4;
    short8 a0 = {0,0,0,0,0,0,0,0}, aD = {0,0,0,0,0,0,0,0};
    if (valid) { a0 = *(const short8*)xr; aD = *(const short8*)(xr + D * 16); }
    f32x4 aF0 = {0.f,0.f,0.f,0.f}, aF1 = {0.f,0.f,0.f,0.f};
    f32x4 aG0 = {0.f,0.f,0.f,0.f}, aG1 = {0.f,0.f,0.f,0.f};
    aF0 = __builtin_amdgcn_mfma_f32_16x16x32_bf16(a0, bf[0][0][0], aF0, 0, 0, 0);
    aF0 = __builtin_amdgcn_mfma_f32_16x16x32_bf16(aD, bf[0][1][0], aF0, 0, 0, 0);
    aF1 = __builtin_amdgcn_mfma_f32_16x16x32_bf16(a0, bf[0][0][1], aF1, 0, 0, 0);
    aF1 = __builtin_amdgcn_mfma_f32_16x16x32_bf16(aD, bf[0][1][1], aF1, 0, 0, 0);
    aG0 = __builtin_amdgcn_mfma_f32_16x16x32_bf16(a0, bf[1][0][0], aG0, 0, 0, 0);
    aG0 = __builtin_amdgcn_mfma_f32_16x16x32_bf16(aD, bf[1][1][0], aG0, 0, 0, 0);
    aG1 = __builtin_amdgcn_mfma_f32_16x16x32_bf16(a0, bf[1][0][1], aG1, 0, 0, 0);
    aG1 = __builtin_amdgcn_mfma_f32_16x16x32_bf16(aD, bf[1][1][1], aG1, 0, 0, 0);
#pragma unroll
    for (int r = 0; r < 4; r++) {
      int lrow = wave * 32 + tile * 16 + q * 4 + r;
      float F0 = aF0[r] + fb0, G0 = aG0[r] + gb0;
      float F1 = aF1[r] + fb1, G1 = aG1[r] + gb1;
      float af0 = fabsf(F0), ef0 = __expf(-2.0f * af0);
      float th0 = copysignf((1.0f - ef0) / (1.0f + ef0), F0);
      float hv0 = th0 * (1.0f / (1.0f + __expf(-G0)));
      float af1 = fabsf(F1), ef1 = __expf(-2.0f * af1);
      float th1 = copysignf((1.0f - ef1) / (1.0f + ef1), F1);
      float hv1 = th1 * (1.0f / (1.0f + __expf(-G1)));
      xst[lrow * RS + m]      = hv0;
      xst[lrow * RS + 16 + m] = hv1;
    }
  }
  __syncthreads();
  {
    uint2* outp = (uint2*)h;
#pragma unroll
    for (int it = 0; it < 4; it++) {
      int l = it * 256 + tid;
      int g = base * 8 + l;
      if (g < nrows * 8) {
        int rl = l >> 3, j4 = l & 7;
        float2 a = *(const float2*)&xst[rl * RS + j4 * 4];
        float2 b = *(const float2*)&xst[rl * RS + j4 * 4 + 2];
        uint2 pv = make_uint2(packbf(a.x, a.y), packbf(b.x, b.y));
        if constexpr (!LAST) outp[g] = pv;
        int grow = base + rl;
        int node = grow / TOUT, tt = grow - node * TOUT;
        if (tt == TOUT - 1) {
          *(uint2*)(hlast + (size_t)node * 128 + layer * 16 + j4 * 2) = pv;
        }
      }
    }
  }
}

// ---------------- one diffusion hop: uint4 gathers, half-wave edge pairing for small rows ------
// Row = CH uint4 (CH = TOUT*4). CH<=32: lanes 0-31 and 32-63 process different edges in parallel,
// merged by shfl_xor(32) at the end. CH>32: one edge per wave iteration, lane = chunk id.
template <int CH>
__global__ __launch_bounds__(256) void k_hop(const uint32* __restrict__ in, uint32* __restrict__ out,
    const int* __restrict__ rowptr, const int* __restrict__ col, const float* __restrict__ deginv) {
  const uint4* src = (const uint4*)in;
  uint4* dst = (uint4*)out;
  int wid = (blockIdx.x * 256 + threadIdx.x) >> 6;
  int lane = threadIdx.x & 63;
  if (wid >= N) return;
  int s = rowptr[wid], e = rowptr[wid + 1];
  float aL0 = 0.f, aL1 = 0.f, aL2 = 0.f, aL3 = 0.f;
  float aH0 = 0.f, aH1 = 0.f, aH2 = 0.f, aH3 = 0.f;

  if constexpr (CH <= 32) {
    int half = lane >> 5, c = lane & 31;
    bool act = c < CH;
    int idx = s;
    for (; idx + 7 < e; idx += 8) {
      int e0 = col[idx + half], e1 = col[idx + half + 2];
      int e2 = col[idx + half + 4], e3 = col[idx + half + 6];
      if (act) {
        uint4 v0 = src[(size_t)e0 * CH + c];
        uint4 v1 = src[(size_t)e1 * CH + c];
        uint4 v2 = src[(size_t)e2 * CH + c];
        uint4 v3 = src[(size_t)e3 * CH + c];
        aL0 += (bflo(v0.x) + bflo(v1.x)) + (bflo(v2.x) + bflo(v3.x));
        aH0 += (bfhi(v0.x) + bfhi(v1.x)) + (bfhi(v2.x) + bfhi(v3.x));
        aL1 += (bflo(v0.y) + bflo(v1.y)) + (bflo(v2.y) + bflo(v3.y));
        aH1 += (bfhi(v0.y) + bfhi(v1.y)) + (bfhi(v2.y) + bfhi(v3.y));
        aL2 += (bflo(v0.z) + bflo(v1.z)) + (bflo(v2.z) + bflo(v3.z));
        aH2 += (bfhi(v0.z) + bfhi(v1.z)) + (bfhi(v2.z) + bfhi(v3.z));
        aL3 += (bflo(v0.w) + bflo(v1.w)) + (bflo(v2.w) + bflo(v3.w));
        aH3 += (bfhi(v0.w) + bfhi(v1.w)) + (bfhi(v2.w) + bfhi(v3.w));
      }
    }
    for (; idx + 1 < e; idx += 2) {
      int e0 = col[idx + half];
      if (act) {
        uint4 v = src[(size_t)e0 * CH + c];
        aL0 += bflo(v.x); aH0 += bfhi(v.x);
        aL1 += bflo(v.y); aH1 += bfhi(v.y);
        aL2 += bflo(v.z); aH2 += bfhi(v.z);
        aL3 += bflo(v.w); aH3 += bfhi(v.w);
      }
    }
    if (idx < e && half == 0 && act) {
      uint4 v = src[(size_t)col[idx] * CH + c];
      aL0 += bflo(v.x); aH0 += bfhi(v.x);
      aL1 += bflo(v.y); aH1 += bfhi(v.y);
      aL2 += bflo(v.z); aH2 += bfhi(v.z);
      aL3 += bflo(v.w); aH3 += bfhi(v.w);
    }
    // merge the two half-wave partial sums
    aL0 += __shfl_xor(aL0, 32); aH0 += __shfl_xor(aH0, 32);
    aL1 += __shfl_xor(aL1, 32); aH1 += __shfl_xor(aH1, 32);
    aL2 += __shfl_xor(aL2, 32); aH2 += __shfl_xor(aH2, 32);
    aL3 += __shfl_xor(aL3, 32); aH3 += __shfl_xor(aH3, 32);
    float inv = deginv[wid];
    if (half == 0 && act) {
      uint4 o;
      o.x = packbf(aL0 * inv, aH0 * inv);
      o.y = packbf(aL1 * inv, aH1 * inv);
      o.z = packbf(aL2 * inv, aH2 * inv);
      o.w = packbf(aL3 * inv, aH3 * inv);
      dst[(size_t)wid * CH + c] = o;
    }
  } else {
    int c = lane;
    bool act = c < CH;
    int idx = s;
    for (; idx + 3 < e; idx += 4) {
      int e0 = col[idx], e1 = col[idx + 1], e2 = col[idx + 2], e3 = col[idx + 3];
      if (act) {
        uint4 v0 = src[(size_t)e0 * CH + c];
        uint4 v1 = src[(size_t)e1 * CH + c];
        uint4 v2 = src[(size_t)e2 * CH + c];
        uint4 v3 = src[(size_t)e3 * CH + c];
        aL0 += (bflo(v0.x) + bflo(v1.x)) + (bflo(v2.x) + bflo(v3.x));
        aH0 += (bfhi(v0.x) + bfhi(v1.x)) + (bfhi(v2.x) + bfhi(v3.x));
        aL1 += (bflo(v0.y) + bflo(v1.y)) + (bflo(v2.y) + bflo(v3.y));
        aH1 += (bfhi(v0.y) + bfhi(v1.y)) + (bfhi(v2.y) + bfhi(v3.y));
        aL2 += (bflo(v0.z) + bflo(v1.z)) + (bflo(v2.z) + bflo(v3.z));
        aH2 += (bfhi(v0.z) + bfhi(v1.z)) + (bfhi(v2.z) + bfhi(v3.z));
        aL3 += (bflo(v0.w) + bflo(v1.w)) + (bflo(v2.w) + bflo(v3.w));
        aH3 += (bfhi(v0.w) + bfhi(v1.w)) + (bfhi(v2.w) + bfhi(v3.w));
      }
    }
    for (; idx < e; ++idx) {
      int e0 = col[idx];
      if (act) {
        uint4 v = src[(size_t)e0 * CH + c];
        aL0 += bflo(v.x); aH0 += bfhi(v.x);
        aL1 += bflo(v.y); aH1 += bfhi(v.y);
        aL2 += bflo(v.z); aH2 += bfhi(v.z);
        aL3 += bflo(v.w); aH3 += bfhi(v.w);
      }
    }
    float inv = deginv[wid];
    if (act) {
      uint4 o;
      o.x = packbf(aL0 * inv, aH0 * inv);
      o.y = packbf(aL1 * inv, aH1 * inv);
      o.z = packbf(aL2 * inv, aH2 * inv);
      o.w = packbf(aL3 * inv, aH3 * inv);
      dst[(size_t)wid * CH + c] = o;
    }
  }
}

// ---------------- combine (MFMA) — partial-buffer BN atomics, NO device fences ----------------
template <int TIN, int TOUT>
__global__ __launch_bounds__(256, 4) void k_combine(const uint32* __restrict__ h,
    const uint32* __restrict__ c1, const uint32* __restrict__ c2, const uint32* __restrict__ c3,
    const uint32* __restrict__ bpack, const float* __restrict__ gcb,
    const uint32* __restrict__ xcur, int layer,
    const float* __restrict__ par,
    uint32* __restrict__ xnext, float* __restrict__ sums) {
  constexpr int RS = 34;
  __shared__ float xst[128 * RS];
  __shared__ float pbuf[96];
  __shared__ float r1s[32], r2s[32];
  int tid = threadIdx.x;
  if (tid < 32) {
    pbuf[tid]      = gcb[layer * 32 + tid];
    pbuf[32 + tid] = par[layer * 64 + tid];
    pbuf[64 + tid] = par[layer * 64 + 32 + tid];
    r1s[tid] = 0.0f; r2s[tid] = 0.0f;
  }

  int nrows = N * TOUT;
  int base = blockIdx.x * 128;
  int wave = tid >> 6, lane = tid & 63;
  int m = lane & 15, q = lane >> 4;

  const uint32* bp = bpack + (size_t)layer * 2048;
  short8 bf[4][2];
#pragma unroll
  for (int s = 0; s < 4; s++)
#pragma unroll
    for (int hh = 0; hh < 2; hh++)
      bf[s][hh] = *(const short8*)(bp + (size_t)((s * 2 + hh) * 64 + lane) * 4);

  f32x4 acc[2][2] = {{{0.f,0.f,0.f,0.f},{0.f,0.f,0.f,0.f}},{{0.f,0.f,0.f,0.f},{0.f,0.f,0.f,0.f}}};
  const uint32* srcs[4] = { h, c1, c2, c3 };
#pragma unroll
  for (int s = 0; s < 4; s++) {
    const uint32* sp = srcs[s];
#pragma unroll
    for (int t = 0; t < 2; t++) {
      int row = base + wave * 32 + t * 16 + m;
      short8 af = {0,0,0,0,0,0,0,0};
      if (row < nrows) af = *(const short8*)(sp + (size_t)row * 16 + q * 4);
      acc[t][0] = __builtin_amdgcn_mfma_f32_16x16x32_bf16(af, bf[s][0], acc[t][0], 0, 0, 0);
      acc[t][1] = __builtin_amdgcn_mfma_f32_16x16x32_bf16(af, bf[s][1], acc[t][1], 0, 0, 0);
    }
  }

  __syncthreads();
#pragma unroll
  for (int t = 0; t < 2; t++)
#pragma unroll
    for (int hh = 0; hh < 2; hh++)
#pragma unroll
      for (int r = 0; r < 4; r++)
        xst[(wave * 32 + t * 16 + q * 4 + r) * RS + hh * 16 + m] = acc[t][hh][r];
  __syncthreads();

  constexpr int toff = TIN - TOUT;
  int rg = tid >> 3, oq = tid & 7;
  float gb0 = pbuf[oq * 4 + 0], gb1 = pbuf[oq * 4 + 1], gb2 = pbuf[oq * 4 + 2], gb3 = pbuf[oq * 4 + 3];
  float sc0 = pbuf[32 + oq * 4 + 0], sc1 = pbuf[32 + oq * 4 + 1], sc2 = pbuf[32 + oq * 4 + 2], sc3 = pbuf[32 + oq * 4 + 3];
  float sh0 = pbuf[64 + oq * 4 + 0], sh1 = pbuf[64 + oq * 4 + 1], sh2 = pbuf[64 + oq * 4 + 2], sh3 = pbuf[64 + oq * 4 + 3];
  float s1[4] = {0.f, 0.f, 0.f, 0.f}, s2[4] = {0.f, 0.f, 0.f, 0.f};
#pragma unroll
  for (int i = 0; i < 4; i++) {
    int r = rg + 32 * i;
    int row = base + r;
    bool act = row < nrows;
    float2 aa = *(const float2*)&xst[r * RS + oq * 4];
    float2 ab = *(const float2*)&xst[r * RS + oq * 4 + 2];
    float xr0 = 0.f, xr1 = 0.f, xr2 = 0.f, xr3 = 0.f;
    if (act) {
      int node = row / TOUT, t_ = row - node * TOUT;
      const uint32* rp = xcur + ((size_t)node * TIN + toff + t_) * 16 + oq * 2;
      uint32 va = rp[0], vb = rp[1];
      xr0 = bflo(va); xr1 = bfhi(va); xr2 = bflo(vb); xr3 = bfhi(vb);
    }
    float v0 = aa.x + gb0 + sc0 * xr0 + sh0;
    float v1 = aa.y + gb1 + sc1 * xr1 + sh1;
    float v2 = ab.x + gb2 + sc2 * xr2 + sh2;
    float v3 = ab.y + gb3 + sc3 * xr3 + sh3;
    *(float2*)&xst[r * RS + oq * 4]     = make_float2(v0, v1);
    *(float2*)&xst[r * RS + oq * 4 + 2] = make_float2(v2, v3);
    if (act) {
      s1[0] += v0; s1[1] += v1; s1[2] += v2; s1[3] += v3;
      s2[0] += v0 * v0; s2[1] += v1 * v1; s2[2] += v2 * v2; s2[3] += v3 * v3;
    }
  }
#pragma unroll
  for (int j = 0; j < 4; j++) {
    atomicAdd(&r1s[oq * 4 + j], s1[j]);
    atomicAdd(&r2s[oq * 4 + j], s2[j]);
  }
  __syncthreads();

  {
    uint2* outp = (uint2*)xnext;
#pragma unroll
    for (int it = 0; it < 4; it++) {
      int l = it * 256 + tid;
      int g = base * 8 + l;
      if (g < nrows * 8) {
        int rl = l >> 3, j4 = l & 7;
        float2 a = *(const float2*)&xst[rl * RS + j4 * 4];
        float2 b = *(const float2*)&xst[rl * RS + j4 * 4 + 2];
        outp[g] = make_uint2(packbf(a.x, a.y), packbf(b.x, b.y));
      }
    }
  }
  // BN partial atomics spread over NPART buffers: sums[(layer*NPART+part)*64 + j]
  {
    int part = blockIdx.x & (NPART - 1);
    float* sp = sums + ((size_t)layer * NPART + part) * 64;
    if (tid < 32) atomicAdd(&sp[tid], r1s[tid]);
    else if (tid < 64) atomicAdd(&sp[tid], r2s[tid - 32]);
  }
}

// ---------------- BN finalize + next-layer conv-weight pack (ONE single-block kernel) ---------
__global__ __launch_bounds__(256) void k_bnprep(const float* __restrict__ sums,
    const float* __restrict__ bng, const float* __restrict__ bnb, float* __restrict__ par,
    const float* __restrict__ fw, const float* __restrict__ fb,
    const float* __restrict__ gw, const float* __restrict__ gb,
    uint32* __restrict__ cpack, int layer, int tout) {
  __shared__ float red1[8][32];
  __shared__ float red2[8][32];
  __shared__ float pb[64];
  int tid = threadIdx.x;
  {
    int o = tid & 31, grp = tid >> 5;
    float t1 = 0.f, t2 = 0.f;
    const float* lp = sums + (size_t)layer * NPART * 64;
    for (int p = grp; p < NPART; p += 8) {
      t1 += lp[p * 64 + o];
      t2 += lp[p * 64 + 32 + o];
    }
    red1[grp][o] = t1; red2[grp][o] = t2;
  }
  __syncthreads();
  if (tid < 32) {
    float t1 = 0.f, t2 = 0.f;
#pragma unroll
    for (int g = 0; g < 8; g++) { t1 += red1[g][tid]; t2 += red2[g][tid]; }
    float cnt = (float)N * (float)tout;
    float mu = t1 / cnt;
    float var = t2 / cnt - mu * mu;
    float sc = bng[layer * 32 + tid] * rsqrtf(var + 1e-5f);
    float sh = bnb[layer * 32 + tid] - mu * sc;
    par[(layer + 1) * 64 + tid] = sc;
    par[(layer + 1) * 64 + 32 + tid] = sh;
    pb[tid] = sc; pb[32 + tid] = sh;
  }
  __syncthreads();
  int nl = layer + 1;
  uint32* cbase = cpack + (size_t)nl * 2176;
  for (int tix = tid; tix < 2048 + 64; tix += 256) {
    if (tix < 2048) {
      int w4 = tix & 3, lane2 = (tix >> 2) & 63, hh2 = (tix >> 8) & 1, ktap = (tix >> 9) & 1, sel = tix >> 10;
      int n2 = lane2 & 15, q2 = lane2 >> 4;
      int c0 = q2 * 8 + w4 * 2, o = hh2 * 16 + n2;
      const float* w = sel ? gw : fw;
      float v0 = w[(((size_t)nl * 32 + o) * 32 + c0) * 2 + ktap] * pb[c0];
      float v1 = w[(((size_t)nl * 32 + o) * 32 + c0 + 1) * 2 + ktap] * pb[c0 + 1];
      cbase[tix] = packbf(v0, v1);
    } else {
      int i = tix - 2048; int sel = i >> 5; int o = i & 31;
      const float* w = sel ? gw : fw;
      const float* b = sel ? gb : fb;
      float s = b[nl * 32 + o];
      for (int c = 0; c < 32; c++) {
        float sh2 = pb[32 + c];
        s += (w[(((size_t)nl * 32 + o) * 32 + c) * 2 + 0] +
              w[(((size_t)nl * 32 + o) * 32 + c) * 2 + 1]) * sh2;
      }
      ((float*)cbase)[2048 + i] = s;
    }
  }
}

// ---------------- head GEMM 1: S = relu(HLbf @ WS2^T + SB), bf16 in, bf16 out ----------------
__global__ __launch_bounds__(256) void k_gemm1(const uint32* __restrict__ A,
    const uint32* __restrict__ bp, const float* __restrict__ bias, uint32* __restrict__ Sb) {
  constexpr int RS = 68;
  __shared__ float xst[128 * RS];
  int tid = threadIdx.x;
  int wave = tid >> 6, lane = tid & 63;
  int m = lane & 15, q = lane >> 4;
  int base = blockIdx.x * 128;
  int ot0 = blockIdx.y * 8;

  f32x4 acc[2][8];
#pragma unroll
  for (int t = 0; t < 2; t++)
#pragma unroll
    for (int nt = 0; nt < 8; nt++) acc[t][nt] = (f32x4){0.f, 0.f, 0.f, 0.f};

  int row0 = base + wave * 32 + m;
  int row1 = row0 + 16;
#pragma unroll 1
  for (int ks = 0; ks < 8; ks++) {
    short8 a0 = {0,0,0,0,0,0,0,0}, a1 = {0,0,0,0,0,0,0,0};
    if (row0 < N) a0 = *(const short8*)(A + (size_t)row0 * 128 + ks * 16 + q * 4);
    if (row1 < N) a1 = *(const short8*)(A + (size_t)row1 * 128 + ks * 16 + q * 4);
#pragma unroll
    for (int nt = 0; nt < 8; nt++) {
      short8 b = *(const short8*)(bp + (size_t)(((ot0 + nt) * 8 + ks) * 64 + lane) * 4);
      acc[0][nt] = __builtin_amdgcn_mfma_f32_16x16x32_bf16(a0, b, acc[0][nt], 0, 0, 0);
      acc[1][nt] = __builtin_amdgcn_mfma_f32_16x16x32_bf16(a1, b, acc[1][nt], 0, 0, 0);
    }
  }

#pragma unroll
  for (int half = 0; half < 2; half++) {
    if (half) __syncthreads();
#pragma unroll
    for (int t = 0; t < 2; t++)
#pragma unroll
      for (int nn = 0; nn < 4; nn++) {
        float bv = bias[blockIdx.y * 128 + (half * 4 + nn) * 16 + m];
#pragma unroll
        for (int r = 0; r < 4; r++) {
          float v = acc[t][half * 4 + nn][r] + bv;
          xst[(wave * 32 + t * 16 + q * 4 + r) * RS + nn * 16 + m] = fmaxf(v, 0.0f);
        }
      }
    __syncthreads();
#pragma unroll
    for (int it = 0; it < 8; it++) {
      int l = it * 256 + tid;
      int rl = l >> 4, c4 = l & 15;
      int grow = base + rl;
      if (grow < N) {
        float2 a = *(const float2*)&xst[rl * RS + c4 * 4];
        float2 b = *(const float2*)&xst[rl * RS + c4 * 4 + 2];
        *(uint2*)(Sb + (size_t)grow * 128 + blockIdx.y * 64 + half * 32 + c4 * 2) =
            make_uint2(packbf(a.x, a.y), packbf(b.x, b.y));
      }
    }
  }
}

// ---------------- head GEMM 2 fused: out += relu(Sbf @ out1_w^T + b1) @ out2_w^T (+ b2) --------
__global__ __launch_bounds__(256) void k_gemm2f(const uint32* __restrict__ A,
    const uint32* __restrict__ bp, const float* __restrict__ bias,
    const uint32* __restrict__ w2p, const float* __restrict__ b2, float* __restrict__ out) {
  constexpr int RS = 68;
  __shared__ float xst[128 * RS];
  int tid = threadIdx.x;
  int wave = tid >> 6, lane = tid & 63;
  int m = lane & 15, q = lane >> 4;
  int base = blockIdx.x * 128;
  int ot0 = blockIdx.y * 8;

  f32x4 acc[2][8];
#pragma unroll
  for (int t = 0; t < 2; t++)
#pragma unroll
    for (int nt = 0; nt < 8; nt++) acc[t][nt] = (f32x4){0.f, 0.f, 0.f, 0.f};

  int row0 = base + wave * 32 + m;
  int row1 = row0 + 16;
#pragma unroll 1
  for (int ks = 0; ks < 8; ks++) {
    short8 a0 = {0,0,0,0,0,0,0,0}, a1 = {0,0,0,0,0,0,0,0};
    if (row0 < N) a0 = *(const short8*)(A + (size_t)row0 * 128 + ks * 16 + q * 4);
    if (row1 < N) a1 = *(const short8*)(A + (size_t)row1 * 128 + ks * 16 + q * 4);
#pragma unroll
    for (int nt = 0; nt < 8; nt++) {
      short8 b = *(const short8*)(bp + (size_t)(((ot0 + nt) * 8 + ks) * 64 + lane) * 4);
      acc[0][nt] = __builtin_amdgcn_mfma_f32_16x16x32_bf16(a0, b, acc[0][nt], 0, 0, 0);
      acc[1][nt] = __builtin_amdgcn_mfma_f32_16x16x32_bf16(a1, b, acc[1][nt], 0, 0, 0);
    }
  }

  f32x4 acc2[2][2];
#pragma unroll
  for (int t = 0; t < 2; t++)
#pragma unroll
    for (int o2 = 0; o2 < 2; o2++) acc2[t][o2] = (f32x4){0.f, 0.f, 0.f, 0.f};

#pragma unroll
  for (int half = 0; half < 2; half++) {
    if (half) __syncthreads();
#pragma unroll
    for (int t = 0; t < 2; t++)
#pragma unroll
      for (int nn = 0; nn < 4; nn++) {
        float bv = bias[blockIdx.y * 128 + (half * 4 + nn) * 16 + m];
#pragma unroll
        for (int r = 0; r < 4; r++) {
          float v = acc[t][half * 4 + nn][r] + bv;
          xst[(wave * 32 + t * 16 + q * 4 + r) * RS + nn * 16 + m] = fmaxf(v, 0.0f);
        }
      }
    __syncthreads();
#pragma unroll
    for (int kl = 0; kl < 2; kl++) {
      short8 a2[2];
#pragma unroll
      for (int t = 0; t < 2; t++) {
        const float* xp = &xst[(size_t)(wave * 32 + t * 16 + m) * RS + kl * 32 + q * 8];
        float4 f0 = *(const float4*)xp;
        float4 f1 = *(const float4*)(xp + 4);
        uint32 u[4];
        u[0] = packbf(f0.x, f0.y); u[1] = packbf(f0.z, f0.w);
        u[2] = packbf(f1.x, f1.y); u[3] = packbf(f1.z, f1.w);
        a2[t] = *(const short8*)u;
      }
      int ksg = blockIdx.y * 4 + half * 2 + kl;
#pragma unroll
      for (int o2 = 0; o2 < 2; o2++) {
        short8 b = *(const short8*)(w2p + (size_t)(((o2 * 16 + ksg) * 64 + lane) * 4));
        acc2[0][o2] = __builtin_amdgcn_mfma_f32_16x16x32_bf16(a2[0], b, acc2[0][o2], 0, 0, 0);
        acc2[1][o2] = __builtin_amdgcn_mfma_f32_16x16x32_bf16(a2[1], b, acc2[1][o2], 0, 0, 0);
      }
    }
  }

#pragma unroll
  for (int t = 0; t < 2; t++)
#pragma unroll
    for (int o2 = 0; o2 < 2; o2++) {
      int oc = o2 * 16 + m;
      if (oc < 24) {
#pragma unroll
        for (int r = 0; r < 4; r++) {
          int row = base + wave * 32 + t * 16 + q * 4 + r;
          if (row < N) {
            float v = acc2[t][o2][r];
            if (blockIdx.y == 0) v += b2[oc];
            atomicAdd(&out[(size_t)row * 24 + oc], v);
          }
        }
      }
    }
}

// ---------------- host side ----------------
struct Ptrs {
  const float *fw, *fb, *gw, *gb, *gcb, *bng, *bnb;
  const uint32 *bpack;
  uint32 *cpack;
  void *H, *C1, *C2, *C3;
  uint32 *HL;
  float *par, *sums;
  const int *row, *col;
  const float *deg;
};

template <int TIN, int TOUT, int D, bool LAST>
static void run_layer(int layer, const Ptrs& P, uint32*& xc, uint32*& xn, hipStream_t stream) {
  int cblocks = (N * TOUT + 127) / 128;
  k_conv<TIN, TOUT, D, LAST><<<cblocks, 256, 0, stream>>>(xc, P.cpack, layer, (uint32*)P.H, P.HL);
  if (!LAST) {
    constexpr int CH = TOUT * 4;   // uint4 chunks per row
    int hb = (N * 64 + 255) / 256;
    k_hop<CH><<<hb, 256, 0, stream>>>((const uint32*)P.H, (uint32*)P.C1, P.row, P.col, P.deg);
    k_hop<CH><<<hb, 256, 0, stream>>>((const uint32*)P.C1, (uint32*)P.C2, P.row, P.col, P.deg);
    k_hop<CH><<<hb, 256, 0, stream>>>((const uint32*)P.C2, (uint32*)P.C3, P.row, P.col, P.deg);
    k_combine<TIN, TOUT><<<cblocks, 256, 0, stream>>>((const uint32*)P.H, (const uint32*)P.C1,
                                                      (const uint32*)P.C2, (const uint32*)P.C3,
                                                      P.bpack, P.gcb, xc, layer, P.par, xn, P.sums);
    k_bnprep<<<1, 256, 0, stream>>>(P.sums, P.bng, P.bnb, P.par, P.fw, P.fb, P.gw, P.gb,
                                    P.cpack, layer, TOUT);
    uint32* tmp = xc; xc = xn; xn = tmp;
  }
}

extern "C" void kernel_launch(void* const* d_in, const int* in_sizes, int n_in,
                              void* d_out, int out_size, void* d_ws, size_t ws_size,
                              hipStream_t stream) {
  const float* inputs  = (const float*)d_in[0];
  const int*   esrc    = (const int*)d_in[1];
  const int*   edst    = (const int*)d_in[2];
  const float* enter_w = (const float*)d_in[3];
  const float* enter_b = (const float*)d_in[4];
  const float* filt_w  = (const float*)d_in[5];
  const float* filt_b  = (const float*)d_in[6];
  const float* gate_w  = (const float*)d_in[7];
  const float* gate_b  = (const float*)d_in[8];
  const float* gc_w    = (const float*)d_in[9];
  const float* gc_b    = (const float*)d_in[10];
  const float* skip_w  = (const float*)d_in[11];
  const float* skip_b  = (const float*)d_in[12];
  const float* bn_g    = (const float*)d_in[13];
  const float* bn_b    = (const float*)d_in[14];
  const float* out1_w  = (const float*)d_in[15];
  const float* out1_b  = (const float*)d_in[16];
  const float* out2_w  = (const float*)d_in[17];
  const float* out2_b  = (const float*)d_in[18];

  char* ws = (char*)d_ws;
  uint32* XA = (uint32*)(ws + XA_OFF);
  uint32* XB = (uint32*)(ws + XB_OFF);
  void* H    = (void*)(ws + H_OFF);
  void* C1   = (void*)(ws + C1_OFF);
  void* C2   = (void*)(ws + C2_OFF);
  void* C3   = (void*)(ws + C3_OFF);
  uint32* HLB = (uint32*)(ws + HL_OFF);     // bf16 [N][128]
  uint32* W2P = (uint32*)(ws + W2P_OFF);
  float* SB  = (float*)(ws + SB_OFF);
  float* SUMS = (float*)(ws + SUMS_OFF);
  float* PAR  = (float*)(ws + PAR_OFF);
  int* CNT  = (int*)(ws + CNT_OFF);
  int* ROW  = (int*)(ws + ROW_OFF);
  int* FILL = (int*)(ws + FILL_OFF);
  int* COL  = (int*)(ws + COL_OFF);
  float* DEG = (float*)(ws + DEG_OFF);
  uint32* BP = (uint32*)(ws + BP_OFF);
  uint32* CP = (uint32*)(ws + CP_OFF);
  uint32* BW1 = (uint32*)(ws + BW1_OFF);
  uint32* BW2 = (uint32*)(ws + BW2_OFF);
  int* BS = (int*)(ws + BS_OFF);
  uint32* Sb  = (uint32*)(ws + S_OFF);      // bf16 S [N][128]

  // one mega-setup launch: zeros (CNT/SUMS/d_out), par identity, all weight packs, enter conv
  k_setup<<<SU_EN1, 256, 0, stream>>>(inputs, enter_w, enter_b, filt_w, filt_b, gate_w, gate_b,
                                      gc_w, skip_w, skip_b, out1_w, out2_w,
                                      CNT, SUMS, (float*)d_out, out_size,
                                      PAR, BP, BW1, BW2, W2P, SB, CP, XA);

  k_count<<<(E + 255) / 256, 256, 0, stream>>>(edst, CNT);
  k_scan1<<<NB_SCAN, 256, 0, stream>>>(CNT, BS);
  k_scan3<<<NB_SCAN, 256, 0, stream>>>(CNT, BS, ROW, FILL, DEG);
  k_scatter<<<(E + 255) / 256, 256, 0, stream>>>(esrc, edst, FILL, COL);

  Ptrs P;
  P.fw = filt_w; P.fb = filt_b; P.gw = gate_w; P.gb = gate_b;
  P.gcb = gc_b; P.bng = bn_g; P.bnb = bn_b; P.bpack = BP; P.cpack = CP;
  P.H = H; P.C1 = C1; P.C2 = C2; P.C3 = C3; P.HL = HLB; P.par = PAR; P.sums = SUMS;
  P.row = ROW; P.col = COL; P.deg = DEG;

  uint32* xc = XA; uint32* xn = XB;
  run_layer<13, 12, 1, false>(0, P, xc, xn, stream);
  run_layer<12, 10, 2, false>(1, P, xc, xn, stream);
  run_layer<10, 9, 1, false>(2, P, xc, xn, stream);
  run_layer<9, 7, 2, false>(3, P, xc, xn, stream);
  run_layer<7, 6, 1, false>(4, P, xc, xn, stream);
  run_layer<6, 4, 2, false>(5, P, xc, xn, stream);
  run_layer<4, 3, 1, false>(6, P, xc, xn, stream);
  run_layer<3, 1, 2, true>(7, P, xc, xn, stream);

  // head: S = relu(HL @ WS2^T + SB) [bf16]; out = relu(S @ out1_w^T + b1) @ out2_w^T + b2 (fused)
  dim3 g1((N + 127) / 128, 2);
  k_gemm1<<<g1, 256, 0, stream>>>(HLB, BW1, SB, Sb);
  dim3 g2((N + 127) / 128, 4);
  k_gemm2f<<<g2, 256, 0, stream>>>(Sb, BW2, out1_b, W2P, out2_b, (float*)d_out);
}